// Round 10
// baseline (2186.873 us; speedup 1.0000x reference)
//
#include <hip/hip_runtime.h>
#include <cstddef>

// B=2 T=512 D=512 V=256 MEM=256 ; M = B*T = 1024
// All inputs fp32 (x is int32); all outputs fp32.
#define F_ELUQK 1
#define F_CAUSAL 2
#define F_DIV 4
#define F_NN 8
#define F_SCALE 16
#define FLAG_STRIDE 32   // u32 units -> 128 B per WG flag line
#define L_WGS 64         // WGs per GRU layer
#define UNITS 8          // hidden units per WG

// ---------- ws layout (float units) ----------
enum : int {
  OFF_QH = 0,                          // [1024][512] hip query
  OFF_GI = 524288,                     // [1024][1536]
  OFF_COMB = OFF_GI + 1572864,         // [1024][2048]  p_f | intent | l_mem | episodes
  OFF_PS = OFF_COMB + 2097152,         // [1024][512]
  OFF_QKV = OFF_PS + 524288,           // [1024][1536]  q(elu+1) | k(elu+1) | v
  OFF_SCORES = OFF_QKV + 1572864,      // [1024][512]
  OFF_DEN = OFF_SCORES + 524288,       // [1024]
  OFF_TMP = OFF_DEN + 1024,            // [1024][512]
  OFF_ATTN = OFF_TMP + 524288,         // [1024][256]
  OFF_SW = OFF_ATTN + 262144,          // [256][512]
  OFF_RING = OFF_SW + 131072,          // u64[4][1024] h_f ring (tagged)  = 8192 floats
  OFF_HSB = OFF_RING + 8192,           // u64[2][1024] h_s dbuf (tagged)  = 4096 floats
  OFF_FLAGS = OFF_HSB + 4096           // flagsB[64*32] (8 KB)
};

// ---------- generic tiled GEMM:  C[m, coff+n] = sum_k A(m,k) * B(n,k)  (+epilogue) ----------
// xidx!=null: A(m,k) = A[xidx[m]*512 + k]  (embedding gather)
__global__ __launch_bounds__(256) void gemm(
    const float* __restrict__ A, int lda, const float* __restrict__ B, int ldb,
    float* __restrict__ C, int ldc, int coff, int K,
    const float* __restrict__ bias, const float* __restrict__ den,
    float scale, int flags, int bBatch, const int* __restrict__ xidx) {
  __shared__ float As[16 * 65];
  __shared__ float Bs[16 * 65];
  int tid = threadIdx.x;
  int n0 = blockIdx.x * 64, m0 = blockIdx.y * 64;
  int rowoff = (m0 >> 9) * bBatch;
  int tx = tid & 15, ty = tid >> 4;

  if ((flags & F_CAUSAL) && n0 > ((m0 & 511) + 63)) {
    #pragma unroll
    for (int i = 0; i < 4; ++i)
      #pragma unroll
      for (int j = 0; j < 4; ++j)
        C[(size_t)(m0 + ty * 4 + i) * ldc + coff + n0 + tx * 4 + j] = 0.f;
    return;
  }

  float acc[4][4] = {};
  for (int k0 = 0; k0 < K; k0 += 16) {
    {
      int rr = tid >> 2, c4 = (tid & 3) << 2;
      int arow = m0 + rr;
      const float* ap = xidx ? (A + (size_t)xidx[arow] * 512 + (k0 + c4))
                             : (A + (size_t)arow * lda + (k0 + c4));
      float4 av = *(const float4*)ap;
      As[(c4 + 0) * 65 + rr] = av.x;
      As[(c4 + 1) * 65 + rr] = av.y;
      As[(c4 + 2) * 65 + rr] = av.z;
      As[(c4 + 3) * 65 + rr] = av.w;
    }
    if (!(flags & F_NN)) {
      int rr = tid >> 2, c4 = (tid & 3) << 2;
      const float* bp = B + (size_t)(n0 + rr + rowoff) * ldb + (k0 + c4);
      float4 bv = *(const float4*)bp;
      Bs[(c4 + 0) * 65 + rr] = bv.x; Bs[(c4 + 1) * 65 + rr] = bv.y;
      Bs[(c4 + 2) * 65 + rr] = bv.z; Bs[(c4 + 3) * 65 + rr] = bv.w;
    } else {
      int kk = tid >> 4, n4 = (tid & 15) << 2;
      const float* bp = B + (size_t)(k0 + kk + rowoff) * ldb + (n0 + n4);
      float4 bv = *(const float4*)bp;
      Bs[kk * 65 + n4 + 0] = bv.x; Bs[kk * 65 + n4 + 1] = bv.y;
      Bs[kk * 65 + n4 + 2] = bv.z; Bs[kk * 65 + n4 + 3] = bv.w;
    }
    __syncthreads();
    #pragma unroll
    for (int k = 0; k < 16; ++k) {
      float av[4], bv[4];
      #pragma unroll
      for (int i = 0; i < 4; ++i) av[i] = As[k * 65 + ty * 4 + i];
      #pragma unroll
      for (int j = 0; j < 4; ++j) bv[j] = Bs[k * 65 + tx * 4 + j];
      #pragma unroll
      for (int i = 0; i < 4; ++i)
        #pragma unroll
        for (int j = 0; j < 4; ++j)
          acc[i][j] = fmaf(av[i], bv[j], acc[i][j]);
    }
    __syncthreads();
  }
  #pragma unroll
  for (int i = 0; i < 4; ++i) {
    int m = m0 + ty * 4 + i;
    float dv = (flags & F_DIV) ? (1.0f / (den[m] + 1e-6f)) : 1.0f;
    #pragma unroll
    for (int j = 0; j < 4; ++j) {
      int n = n0 + tx * 4 + j;
      float v = acc[i][j];
      if (bias) v += bias[n];
      if (flags & F_ELUQK) { if (n < 1024) v = (v > 0.f) ? (v + 1.f) : __expf(v); }
      if (flags & F_CAUSAL) { if (n > (m & 511)) v = 0.f; }
      if (flags & F_SCALE) v *= scale;
      if (flags & F_DIV) v *= dv;
      C[(size_t)m * ldc + coff + n] = v;
    }
  }
}

// ---------- merged qkv / gate / hip_q projections (A = PS, K=512, NT) ----------
__global__ __launch_bounds__(256) void gemm3(
    const float* __restrict__ A,
    const float* __restrict__ qkvw, const float* __restrict__ qkvb,
    const float* __restrict__ gatew, const float* __restrict__ gateb,
    const float* __restrict__ hipw, const float* __restrict__ hipb,
    float* __restrict__ QKV, float* __restrict__ TMP, float* __restrict__ QH) {
  __shared__ float As[16 * 65];
  __shared__ float Bs[16 * 65];
  int tid = threadIdx.x;
  int n0 = blockIdx.x * 64, m0 = blockIdx.y * 64;
  const float* B; const float* bias; float* C; int ldc, base;
  if (n0 < 1536) { B = qkvw; bias = qkvb; C = QKV; ldc = 1536; base = 0; }
  else if (n0 < 2048) { B = gatew; bias = gateb; C = TMP; ldc = 512; base = 1536; }
  else { B = hipw; bias = hipb; C = QH; ldc = 512; base = 2048; }
  int tx = tid & 15, ty = tid >> 4;
  float acc[4][4] = {};
  for (int k0 = 0; k0 < 512; k0 += 16) {
    {
      int rr = tid >> 2, c4 = (tid & 3) << 2;
      const float* ap = A + (size_t)(m0 + rr) * 512 + (k0 + c4);
      float4 av = *(const float4*)ap;
      As[(c4 + 0) * 65 + rr] = av.x; As[(c4 + 1) * 65 + rr] = av.y;
      As[(c4 + 2) * 65 + rr] = av.z; As[(c4 + 3) * 65 + rr] = av.w;
    }
    {
      int rr = tid >> 2, c4 = (tid & 3) << 2;
      const float* bp = B + (size_t)(n0 - base + rr) * 512 + (k0 + c4);
      float4 bv = *(const float4*)bp;
      Bs[(c4 + 0) * 65 + rr] = bv.x; Bs[(c4 + 1) * 65 + rr] = bv.y;
      Bs[(c4 + 2) * 65 + rr] = bv.z; Bs[(c4 + 3) * 65 + rr] = bv.w;
    }
    __syncthreads();
    #pragma unroll
    for (int k = 0; k < 16; ++k) {
      float av[4], bv[4];
      #pragma unroll
      for (int i = 0; i < 4; ++i) av[i] = As[k * 65 + ty * 4 + i];
      #pragma unroll
      for (int j = 0; j < 4; ++j) bv[j] = Bs[k * 65 + tx * 4 + j];
      #pragma unroll
      for (int i = 0; i < 4; ++i)
        #pragma unroll
        for (int j = 0; j < 4; ++j)
          acc[i][j] = fmaf(av[i], bv[j], acc[i][j]);
    }
    __syncthreads();
  }
  #pragma unroll
  for (int i = 0; i < 4; ++i) {
    int m = m0 + ty * 4 + i;
    #pragma unroll
    for (int j = 0; j < 4; ++j) {
      int n = n0 + tx * 4 + j;
      float v = acc[i][j] + bias[n - base];
      if (n < 1024) v = (v > 0.f) ? (v + 1.f) : __expf(v);
      C[(size_t)m * ldc + (n - base)] = v;
    }
  }
}

// ---------- sync helpers (relaxed agent ops only — no cache maintenance) ----------
__device__ __forceinline__ void post_flag(unsigned* flags, int w, unsigned v) {
  __hip_atomic_store(flags + (size_t)w * FLAG_STRIDE, v, __ATOMIC_RELAXED,
                     __HIP_MEMORY_SCOPE_AGENT);
}
__device__ __forceinline__ void poll64(const unsigned* flags, unsigned tgt, int lane) {
  const unsigned* p = flags + (size_t)lane * FLAG_STRIDE;
  while (__hip_atomic_load(p, __ATOMIC_RELAXED, __HIP_MEMORY_SCOPE_AGENT) < tgt)
    __builtin_amdgcn_s_sleep(1);
}
// Poll 8 tagged words (tag == want) and stage the payload floats into LDS.
// Word w = src[(kbase+k)*64 + lane]; payload -> dst[(kbase+k)*64 + lane].
__device__ __forceinline__ void stage8(const unsigned long long* __restrict__ src,
                                       float* __restrict__ dst,
                                       unsigned want, int lane, int kbase) {
  unsigned long long v[8];
  unsigned need = 0xffu;
  while (need) {
    #pragma unroll
    for (int k = 0; k < 8; ++k)
      if (need >> k & 1)
        v[k] = __hip_atomic_load(src + (size_t)(kbase + k) * 64 + lane,
                                 __ATOMIC_RELAXED, __HIP_MEMORY_SCOPE_AGENT);
    unsigned nn = 0;
    #pragma unroll
    for (int k = 0; k < 8; ++k)
      if ((need >> k & 1) && (unsigned)(v[k] >> 32) != want) nn |= 1u << k;
    if (nn) __builtin_amdgcn_s_sleep(1);
    need = nn;
  }
  #pragma unroll
  for (int k = 0; k < 8; ++k)
    dst[(kbase + k) * 64 + lane] = __uint_as_float((unsigned)v[k]);
}

// ---------- fused two-layer pipelined GRU: tagged-word sync ----------
// 128 WGs: 0..63 layer1 (fast), 64..127 layer2 (slow, lags 1 round).
// h broadcast as tagged u64 words {round_tag, f32}: a single relaxed 8B store
// is both data and flag -> consumer poll returns the payload (1 LLC trip).
// Ring (h_f) depth 4; h_s double buffer; flagsB = L2 progress (ring overwrite
// throttle only). 2 __syncthreads per round; gate's 'hold' captured pre-syncB.
__global__ __launch_bounds__(256, 1) void gru2_kernel(
    const float* __restrict__ gi,       // gi_f [1024][1536]
    const float* __restrict__ fwhh, const float* __restrict__ fbhh,
    const float* __restrict__ h0f,
    const float* __restrict__ swih, const float* __restrict__ sbih,
    const float* __restrict__ swhh, const float* __restrict__ sbhh,
    const float* __restrict__ h0s,
    float* __restrict__ pf_out,         // COMB cols [0,512), ld 2048
    float* __restrict__ ps_out,         // PS, ld 512
    float* __restrict__ hfT, float* __restrict__ hsT,
    unsigned long long* __restrict__ ringq,   // [4][1024] tagged
    unsigned long long* __restrict__ hsq,     // [2][1024] tagged
    unsigned* __restrict__ flagsB) {
  __shared__ __attribute__((aligned(16))) float hl[1024];   // own-layer h
  __shared__ __attribute__((aligned(16))) float hfs[1024];  // p_f input (L2)
  __shared__ float P[48];
  __shared__ float Q[48];
  __shared__ float bl[24];
  __shared__ float bi[24];
  int tid = threadIdx.x, wg = blockIdx.x;
  bool L1 = wg < L_WGS;
  int j0 = (wg & (L_WGS - 1)) * UNITS;
  int part = tid & 7, r = tid >> 3;    // r in 0..31; active r<24
  int g = r >> 3, u = r & 7;           // gate, unit
  int wave = tid >> 6, lane = tid & 63;
  const float* whh = L1 ? fwhh : swhh;
  const float* bhh = L1 ? fbhh : sbhh;

  float4 wh[16], wi[16];
  if (r < 24) {
    const float* wp = whh + (size_t)(g * 512 + j0 + u) * 512 + part * 4;
    #pragma unroll
    for (int i = 0; i < 16; ++i) wh[i] = *(const float4*)(wp + i * 32);
    if (!L1) {
      const float* wp2 = swih + (size_t)(g * 512 + j0 + u) * 512 + part * 4;
      #pragma unroll
      for (int i = 0; i < 16; ++i) wi[i] = *(const float4*)(wp2 + i * 32);
    }
  }
  if (tid < 24) {
    bl[tid] = bhh[(tid >> 3) * 512 + j0 + (tid & 7)];
    if (!L1) bi[tid] = sbih[(tid >> 3) * 512 + j0 + (tid & 7)];
  }

  const float4* h4 = (const float4*)hl;
  const float4* f4v = (const float4*)hfs;

  if (L1) {
    for (int t = 0; t < 512; ++t) {
      float i_r = 0.f, i_z = 0.f, i_n = 0.f;
      if (tid < 16) {   // issue gi loads early (in flight during poll)
        int b = tid >> 3, jl = tid & 7;
        const float* girow = gi + (size_t)(b * 512 + t) * 1536 + j0 + jl;
        i_r = girow[0]; i_z = girow[512]; i_n = girow[1024];
      }
      if (t == 0) {
        if (wave < 2) {
          #pragma unroll
          for (int k = 0; k < 8; ++k)
            hl[(wave * 8 + k) * 64 + lane] = h0f[(wave * 8 + k) * 64 + lane];
        }
      } else {
        const unsigned long long* src = ringq + (size_t)((t - 1) & 3) * 1024;
        if (wave == 0) stage8(src, hl, (unsigned)t, lane, 0);
        else if (wave == 1) stage8(src, hl, (unsigned)t, lane, 8);
      }
      if (wave == 2 && t >= 4) poll64(flagsB, (unsigned)(t - 3), lane);
      __syncthreads();
      if (r < 24) {
        float a0 = 0.f, a1 = 0.f;
        #pragma unroll
        for (int i = 0; i < 16; ++i) {
          float4 w = wh[i];
          float4 x0 = h4[i * 8 + part];
          float4 x1 = h4[128 + i * 8 + part];
          a0 += w.x * x0.x + w.y * x0.y + w.z * x0.z + w.w * x0.w;
          a1 += w.x * x1.x + w.y * x1.y + w.z * x1.z + w.w * x1.w;
        }
        a0 += __shfl_xor(a0, 1); a0 += __shfl_xor(a0, 2); a0 += __shfl_xor(a0, 4);
        a1 += __shfl_xor(a1, 1); a1 += __shfl_xor(a1, 2); a1 += __shfl_xor(a1, 4);
        if (part == 0) { P[r] = a0; P[24 + r] = a1; }
      }
      float hold = 0.f;
      if (tid < 16) hold = hl[(tid >> 3) * 512 + j0 + (tid & 7)];
      __syncthreads();
      if (tid < 16) {
        int b = tid >> 3, u2 = tid & 7, j = j0 + u2;
        float gh_r = P[b * 24 + u2] + bl[u2];
        float gh_z = P[b * 24 + 8 + u2] + bl[8 + u2];
        float gh_n = P[b * 24 + 16 + u2] + bl[16 + u2];
        float rg = 1.0f / (1.0f + __expf(-(i_r + gh_r)));
        float zg = 1.0f / (1.0f + __expf(-(i_z + gh_z)));
        float ng = tanhf(i_n + rg * gh_n);
        float hnew = (1.0f - zg) * ng + zg * hold;
        unsigned long long pk = ((unsigned long long)(unsigned)(t + 1) << 32) |
                                (unsigned long long)__float_as_uint(hnew);
        __hip_atomic_store(ringq + (size_t)(t & 3) * 1024 + b * 512 + j, pk,
                           __ATOMIC_RELAXED, __HIP_MEMORY_SCOPE_AGENT);
        pf_out[(size_t)(b * 512 + t) * 2048 + j] = hnew;
        if (t == 511) hfT[b * 512 + j] = hnew;
      }
      // no third sync: wave0's next staging follows its own gate in program
      // order; other waves' next compute is gated by the next first sync.
    }
  } else {
    for (int t2 = 0; t2 < 512; ++t2) {
      {
        const unsigned long long* src = ringq + (size_t)(t2 & 3) * 1024;
        if (wave == 0) stage8(src, hfs, (unsigned)(t2 + 1), lane, 0);
        else if (wave == 1) stage8(src, hfs, (unsigned)(t2 + 1), lane, 8);
        else if (t2 == 0) {
          #pragma unroll
          for (int k = 0; k < 8; ++k)
            hl[((wave - 2) * 8 + k) * 64 + lane] = h0s[((wave - 2) * 8 + k) * 64 + lane];
        } else {
          const unsigned long long* s2 = hsq + (size_t)((t2 - 1) & 1) * 1024;
          if (wave == 2) stage8(s2, hl, (unsigned)t2, lane, 0);
          else stage8(s2, hl, (unsigned)t2, lane, 8);
        }
      }
      __syncthreads();
      if (tid == 0) post_flag(flagsB, wg - L_WGS, (unsigned)(t2 + 1));  // ring slot consumed
      if (r < 24) {
        float a0 = 0.f, a1 = 0.f, c0 = 0.f, c1 = 0.f;
        #pragma unroll
        for (int i = 0; i < 16; ++i) {
          float4 w = wh[i];
          float4 x0 = h4[i * 8 + part];
          float4 x1 = h4[128 + i * 8 + part];
          a0 += w.x * x0.x + w.y * x0.y + w.z * x0.z + w.w * x0.w;
          a1 += w.x * x1.x + w.y * x1.y + w.z * x1.z + w.w * x1.w;
          float4 v = wi[i];
          float4 y0 = f4v[i * 8 + part];
          float4 y1 = f4v[128 + i * 8 + part];
          c0 += v.x * y0.x + v.y * y0.y + v.z * y0.z + v.w * y0.w;
          c1 += v.x * y1.x + v.y * y1.y + v.z * y1.z + v.w * y1.w;
        }
        a0 += __shfl_xor(a0, 1); a0 += __shfl_xor(a0, 2); a0 += __shfl_xor(a0, 4);
        a1 += __shfl_xor(a1, 1); a1 += __shfl_xor(a1, 2); a1 += __shfl_xor(a1, 4);
        c0 += __shfl_xor(c0, 1); c0 += __shfl_xor(c0, 2); c0 += __shfl_xor(c0, 4);
        c1 += __shfl_xor(c1, 1); c1 += __shfl_xor(c1, 2); c1 += __shfl_xor(c1, 4);
        if (part == 0) { P[r] = a0; P[24 + r] = a1; Q[r] = c0; Q[24 + r] = c1; }
      }
      float hold = 0.f;
      if (tid < 16) hold = hl[(tid >> 3) * 512 + j0 + (tid & 7)];
      __syncthreads();
      if (tid < 16) {
        int b = tid >> 3, u2 = tid & 7, j = j0 + u2;
        float i_r = Q[b * 24 + u2] + bi[u2];
        float i_z = Q[b * 24 + 8 + u2] + bi[8 + u2];
        float i_n = Q[b * 24 + 16 + u2] + bi[16 + u2];
        float gh_r = P[b * 24 + u2] + bl[u2];
        float gh_z = P[b * 24 + 8 + u2] + bl[8 + u2];
        float gh_n = P[b * 24 + 16 + u2] + bl[16 + u2];
        float rg = 1.0f / (1.0f + __expf(-(i_r + gh_r)));
        float zg = 1.0f / (1.0f + __expf(-(i_z + gh_z)));
        float ng = tanhf(i_n + rg * gh_n);
        float hnew = (1.0f - zg) * ng + zg * hold;
        unsigned long long pk = ((unsigned long long)(unsigned)(t2 + 1) << 32) |
                                (unsigned long long)__float_as_uint(hnew);
        __hip_atomic_store(hsq + (size_t)(t2 & 1) * 1024 + b * 512 + j, pk,
                           __ATOMIC_RELAXED, __HIP_MEMORY_SCOPE_AGENT);
        ps_out[(size_t)(b * 512 + t2) * 512 + j] = hnew;
        if (t2 == 511) hsT[b * 512 + j] = hnew;
      }
    }
  }
}

// ---------- row reductions ----------
__global__ __launch_bounds__(256) void rowsum_kernel(const float* __restrict__ S,
                                                     float* __restrict__ den) {
  int m = blockIdx.x, tid = threadIdx.x;
  float s = S[(size_t)m * 512 + tid] + S[(size_t)m * 512 + 256 + tid];
  #pragma unroll
  for (int off = 32; off > 0; off >>= 1) s += __shfl_down(s, off);
  __shared__ float r4[4];
  if ((tid & 63) == 0) r4[tid >> 6] = s;
  __syncthreads();
  if (tid == 0) den[m] = r4[0] + r4[1] + r4[2] + r4[3];
}

__global__ __launch_bounds__(256) void softmax_kernel(float* __restrict__ a) {
  int m = blockIdx.x, tid = threadIdx.x;
  float v = a[(size_t)m * 256 + tid];
  float mx = v;
  #pragma unroll
  for (int off = 32; off > 0; off >>= 1) mx = fmaxf(mx, __shfl_down(mx, off));
  __shared__ float r4[4];
  __shared__ float s4[4];
  if ((tid & 63) == 0) r4[tid >> 6] = mx;
  __syncthreads();
  mx = fmaxf(fmaxf(r4[0], r4[1]), fmaxf(r4[2], r4[3]));
  float e = __expf(v - mx);
  float s = e;
  #pragma unroll
  for (int off = 32; off > 0; off >>= 1) s += __shfl_down(s, off);
  if ((tid & 63) == 0) s4[tid >> 6] = s;
  __syncthreads();
  s = s4[0] + s4[1] + s4[2] + s4[3];
  a[(size_t)m * 256 + tid] = e / s;
}

__global__ __launch_bounds__(256) void ln_kernel(
    const float* __restrict__ src, float* __restrict__ dst, int ldd, int dcoff,
    const float* __restrict__ gv, const float* __restrict__ bv, int tanhFirst) {
  int m = blockIdx.x, tid = threadIdx.x;
  float x0 = src[(size_t)m * 512 + tid];
  float x1 = src[(size_t)m * 512 + 256 + tid];
  if (tanhFirst) { x0 = tanhf(x0); x1 = tanhf(x1); }
  float s = x0 + x1, ss = x0 * x0 + x1 * x1;
  #pragma unroll
  for (int off = 32; off > 0; off >>= 1) { s += __shfl_down(s, off); ss += __shfl_down(ss, off); }
  __shared__ float rs[4], rss[4];
  if ((tid & 63) == 0) { rs[tid >> 6] = s; rss[tid >> 6] = ss; }
  __syncthreads();
  float st = rs[0] + rs[1] + rs[2] + rs[3];
  float sst = rss[0] + rss[1] + rss[2] + rss[3];
  float mean = st * (1.0f / 512.0f);
  float var = sst * (1.0f / 512.0f) - mean * mean;
  float inv = rsqrtf(var + 1e-5f);
  float y0 = (x0 - mean) * inv * gv[tid] + bv[tid];
  float y1 = (x1 - mean) * inv * gv[256 + tid] + bv[256 + tid];
  if (!tanhFirst) { y0 = tanhf(y0); y1 = tanhf(y1); }
  dst[(size_t)m * ldd + dcoff + tid] = y0;
  dst[(size_t)m * ldd + dcoff + 256 + tid] = y1;
}

__global__ __launch_bounds__(256) void swnorm_kernel(const float* __restrict__ soma,
                                                     float* __restrict__ sw) {
  int r = blockIdx.x, tid = threadIdx.x;
  float x0 = soma[(size_t)r * 512 + tid];
  float x1 = soma[(size_t)r * 512 + 256 + tid];
  float ss = x0 * x0 + x1 * x1;
  #pragma unroll
  for (int off = 32; off > 0; off >>= 1) ss += __shfl_down(ss, off);
  __shared__ float r4[4];
  if ((tid & 63) == 0) r4[tid >> 6] = ss;
  __syncthreads();
  float norm = sqrtf(r4[0] + r4[1] + r4[2] + r4[3]);
  norm = fmaxf(norm, 1e-12f);
  float inv = 1.0f / norm;
  sw[(size_t)r * 512 + tid] = x0 * inv;
  sw[(size_t)r * 512 + 256 + tid] = x1 * inv;
}

// ---------- host ----------
extern "C" void kernel_launch(void* const* d_in, const int* in_sizes, int n_in,
                              void* d_out, int out_size, void* d_ws, size_t ws_size,
                              hipStream_t stream) {
  (void)in_sizes; (void)n_in; (void)out_size; (void)ws_size;
  float* W = (float*)d_ws;
  float* outf = (float*)d_out;
  // out layout (floats): logits[262144] | thought[524288] | hf1[1024] | hs1[1024]
  const int* x = (const int*)d_in[0];
  const float* soma = (const float*)d_in[3];

  hipMemsetAsync((char*)d_ws + (size_t)OFF_FLAGS * 4, 0, 8192, stream);

  // gi_f = embed-gather(soma,x) @ fast_wih^T + fast_bih   (embed fused via xidx)
  gemm<<<dim3(24, 16), 256, 0, stream>>>(soma, 512, (const float*)d_in[4], 512,
      W + OFF_GI, 1536, 0, 512, (const float*)d_in[6], nullptr, 1.f, 0, 0, x);

  // fused GRU1+GRU2 -> p_f (COMB cols [0,512)), p_s (PS), hf1/hs1 -> out
  gru2_kernel<<<2 * L_WGS, 256, 0, stream>>>(W + OFF_GI,
      (const float*)d_in[5], (const float*)d_in[7], (const float*)d_in[1],
      (const float*)d_in[8], (const float*)d_in[10],
      (const float*)d_in[9], (const float*)d_in[11], (const float*)d_in[2],
      W + OFF_COMB, W + OFF_PS, outf + 786432, outf + 787456,
      (unsigned long long*)(W + OFF_RING), (unsigned long long*)(W + OFF_HSB),
      (unsigned*)(W + OFF_FLAGS));

  // merged: qkv (elu+1 on q,k) -> QKV ; gate pre -> TMP ; hip query -> QH
  gemm3<<<dim3(40, 16), 256, 0, stream>>>(W + OFF_PS,
      (const float*)d_in[12], (const float*)d_in[13],
      (const float*)d_in[14], (const float*)d_in[15],
      (const float*)d_in[19], (const float*)d_in[20],
      W + OFF_QKV, W + OFF_TMP, W + OFF_QH);

  // scores = causal(q k^T) per batch
  gemm<<<dim3(8, 16), 256, 0, stream>>>(W + OFF_QKV, 1536, W + OFF_QKV + 512, 1536,
      W + OFF_SCORES, 512, 0, 512, nullptr, nullptr, 1.f, F_CAUSAL, 512, nullptr);

  rowsum_kernel<<<1024, 256, 0, stream>>>(W + OFF_SCORES, W + OFF_DEN);

  // l_mem = (scores @ v) / (den + 1e-6) -> combined cols [1024,1536)
  gemm<<<dim3(8, 16), 256, 0, stream>>>(W + OFF_SCORES, 512, W + OFF_QKV + 1024, 1536,
      W + OFF_COMB, 2048, 1024, 512, nullptr, W + OFF_DEN, 1.f, F_NN | F_DIV, 512, nullptr);

  // intent = tanh(LN(gate pre)) -> combined cols [512,1024)
  ln_kernel<<<1024, 256, 0, stream>>>(W + OFF_TMP, W + OFF_COMB, 2048, 512,
      (const float*)d_in[16], (const float*)d_in[17], 0);

  // hippocampus attention -> combined cols [1536,2048)
  gemm<<<dim3(4, 16), 256, 0, stream>>>(W + OFF_QH, 512, (const float*)d_in[18], 512,
      W + OFF_ATTN, 256, 0, 512, nullptr, nullptr, 0.04419417382415922f, F_SCALE, 0, nullptr);
  softmax_kernel<<<1024, 256, 0, stream>>>(W + OFF_ATTN);
  gemm<<<dim3(8, 16), 256, 0, stream>>>(W + OFF_ATTN, 256, (const float*)d_in[18], 512,
      W + OFF_COMB, 2048, 1536, 256, nullptr, nullptr, 1.f, F_NN, 0, nullptr);

  // axon + LN -> thought directly into out (fp32)
  gemm<<<dim3(8, 16), 256, 0, stream>>>(W + OFF_COMB, 2048, (const float*)d_in[21], 2048,
      W + OFF_TMP, 512, 0, 2048, (const float*)d_in[22], nullptr, 1.f, 0, 0, nullptr);
  ln_kernel<<<1024, 256, 0, stream>>>(W + OFF_TMP, outf + 262144, 512, 0,
      (const float*)d_in[23], (const float*)d_in[24], 1);

  // logits = (thought @ sw^T) * 16 -> out (fp32)
  swnorm_kernel<<<256, 256, 0, stream>>>(soma, W + OFF_SW);
  gemm<<<dim3(4, 16), 256, 0, stream>>>(outf + 262144, 512, W + OFF_SW, 512,
      outf, 256, 0, 512, nullptr, nullptr, 16.f, F_SCALE, 0, nullptr);
}

// Round 11
// 2170.629 us; speedup vs baseline: 1.0075x; 1.0075x over previous
//
#include <hip/hip_runtime.h>
#include <cstddef>

// B=2 T=512 D=512 V=256 MEM=256 ; M = B*T = 1024
// All inputs fp32 (x is int32); all outputs fp32.
#define F_ELUQK 1
#define F_CAUSAL 2
#define F_DIV 4
#define F_NN 8
#define F_SCALE 16
#define F_ROWSUM 32
#define FLAG_STRIDE 32   // u32 units -> 128 B per WG flag line
#define L_WGS 64         // WGs per GRU layer
#define UNITS 8          // hidden units per WG

// ---------- ws layout (float units) ----------
enum : int {
  OFF_QH = 0,                          // [1024][512] hip query / axon K-chunk-1 acc
  OFF_GI = 524288,                     // [1024][1536]
  OFF_COMB = OFF_GI + 1572864,         // [1024][2048]  p_f | intent | l_mem | episodes
  OFF_PS = OFF_COMB + 2097152,         // [1024][512]
  OFF_QKV = OFF_PS + 524288,           // [1024][1536]  q(elu+1) | k(elu+1) | v
  OFF_SCORES = OFF_QKV + 1572864,      // [1024][512]
  OFF_DEN = OFF_SCORES + 524288,       // [1024]
  OFF_TMP = OFF_DEN + 1024,            // [1024][512]
  OFF_ATTN = OFF_TMP + 524288,         // [1024][256]
  OFF_SWN = OFF_ATTN + 262144,         // [256] 16/||soma_row||
  OFF_RING = OFF_SWN + 256,            // [4][1024]  h_f ring
  OFF_HSB = OFF_RING + 4096,           // [2][1024]  h_s double buffer
  OFF_FLAGS = OFF_HSB + 2048           // flagsA[64*32] | flagsB[64*32]  (16 KB)
};

// ---------- generic tiled GEMM:  C[m, coff+n] = sum_k A(m,k) * B(n,k)  (+epilogue) ----------
// xidx: embedding gather on A rows. blockIdx.z=1: shift A,B by kzoff, write Cz, no bias.
// F_ROWSUM: atomicAdd per-row sums of stored values into rsum (pre-zeroed).
__global__ __launch_bounds__(256) void gemm(
    const float* __restrict__ A, int lda, const float* __restrict__ B, int ldb,
    float* __restrict__ C, int ldc, int coff, int K,
    const float* __restrict__ bias, const float* __restrict__ den,
    const float* __restrict__ cscale, float* __restrict__ rsum,
    float scale, int flags, int bBatch, const int* __restrict__ xidx,
    float* __restrict__ Cz, int kzoff) {
  __shared__ float As[16 * 65];
  __shared__ float Bs[16 * 65];
  int tid = threadIdx.x;
  int n0 = blockIdx.x * 64, m0 = blockIdx.y * 64;
  if (blockIdx.z) { A += kzoff; B += kzoff; C = Cz; bias = nullptr; }
  int rowoff = (m0 >> 9) * bBatch;
  int tx = tid & 15, ty = tid >> 4;

  if ((flags & F_CAUSAL) && n0 > ((m0 & 511) + 63)) {
    #pragma unroll
    for (int i = 0; i < 4; ++i)
      #pragma unroll
      for (int j = 0; j < 4; ++j)
        C[(size_t)(m0 + ty * 4 + i) * ldc + coff + n0 + tx * 4 + j] = 0.f;
    return;
  }

  float acc[4][4] = {};
  for (int k0 = 0; k0 < K; k0 += 16) {
    {
      int rr = tid >> 2, c4 = (tid & 3) << 2;
      int arow = m0 + rr;
      const float* ap = xidx ? (A + (size_t)xidx[arow] * 512 + (k0 + c4))
                             : (A + (size_t)arow * lda + (k0 + c4));
      float4 av = *(const float4*)ap;
      As[(c4 + 0) * 65 + rr] = av.x;
      As[(c4 + 1) * 65 + rr] = av.y;
      As[(c4 + 2) * 65 + rr] = av.z;
      As[(c4 + 3) * 65 + rr] = av.w;
    }
    if (!(flags & F_NN)) {
      int rr = tid >> 2, c4 = (tid & 3) << 2;
      const float* bp = B + (size_t)(n0 + rr + rowoff) * ldb + (k0 + c4);
      float4 bv = *(const float4*)bp;
      Bs[(c4 + 0) * 65 + rr] = bv.x; Bs[(c4 + 1) * 65 + rr] = bv.y;
      Bs[(c4 + 2) * 65 + rr] = bv.z; Bs[(c4 + 3) * 65 + rr] = bv.w;
    } else {
      int kk = tid >> 4, n4 = (tid & 15) << 2;
      const float* bp = B + (size_t)(k0 + kk + rowoff) * ldb + (n0 + n4);
      float4 bv = *(const float4*)bp;
      Bs[kk * 65 + n4 + 0] = bv.x; Bs[kk * 65 + n4 + 1] = bv.y;
      Bs[kk * 65 + n4 + 2] = bv.z; Bs[kk * 65 + n4 + 3] = bv.w;
    }
    __syncthreads();
    #pragma unroll
    for (int k = 0; k < 16; ++k) {
      float av[4], bv[4];
      #pragma unroll
      for (int i = 0; i < 4; ++i) av[i] = As[k * 65 + ty * 4 + i];
      #pragma unroll
      for (int j = 0; j < 4; ++j) bv[j] = Bs[k * 65 + tx * 4 + j];
      #pragma unroll
      for (int i = 0; i < 4; ++i)
        #pragma unroll
        for (int j = 0; j < 4; ++j)
          acc[i][j] = fmaf(av[i], bv[j], acc[i][j]);
    }
    __syncthreads();
  }
  float rs[4] = {0.f, 0.f, 0.f, 0.f};
  #pragma unroll
  for (int i = 0; i < 4; ++i) {
    int m = m0 + ty * 4 + i;
    float dv = (flags & F_DIV) ? (1.0f / (den[m] + 1e-6f)) : 1.0f;
    #pragma unroll
    for (int j = 0; j < 4; ++j) {
      int n = n0 + tx * 4 + j;
      float v = acc[i][j];
      if (bias) v += bias[n];
      if (flags & F_ELUQK) { if (n < 1024) v = (v > 0.f) ? (v + 1.f) : __expf(v); }
      if (flags & F_CAUSAL) { if (n > (m & 511)) v = 0.f; }
      if (flags & F_SCALE) v *= scale;
      if (cscale) v *= cscale[coff + n];
      if (flags & F_DIV) v *= dv;
      C[(size_t)m * ldc + coff + n] = v;
      if (flags & F_ROWSUM) rs[i] += v;
    }
  }
  if (flags & F_ROWSUM) {
    #pragma unroll
    for (int i = 0; i < 4; ++i) {
      float s = rs[i];
      s += __shfl_xor(s, 1); s += __shfl_xor(s, 2);
      s += __shfl_xor(s, 4); s += __shfl_xor(s, 8);
      if (tx == 0) atomicAdd(rsum + (m0 + ty * 4 + i), s);
    }
  }
}

// ---------- merged qkv / gate / hip_q projections (A = PS, K=512, NT) ----------
__global__ __launch_bounds__(256) void gemm3(
    const float* __restrict__ A,
    const float* __restrict__ qkvw, const float* __restrict__ qkvb,
    const float* __restrict__ gatew, const float* __restrict__ gateb,
    const float* __restrict__ hipw, const float* __restrict__ hipb,
    float* __restrict__ QKV, float* __restrict__ TMP, float* __restrict__ QH) {
  __shared__ float As[16 * 65];
  __shared__ float Bs[16 * 65];
  int tid = threadIdx.x;
  int n0 = blockIdx.x * 64, m0 = blockIdx.y * 64;
  const float* B; const float* bias; float* C; int ldc, base;
  if (n0 < 1536) { B = qkvw; bias = qkvb; C = QKV; ldc = 1536; base = 0; }
  else if (n0 < 2048) { B = gatew; bias = gateb; C = TMP; ldc = 512; base = 1536; }
  else { B = hipw; bias = hipb; C = QH; ldc = 512; base = 2048; }
  int tx = tid & 15, ty = tid >> 4;
  float acc[4][4] = {};
  for (int k0 = 0; k0 < 512; k0 += 16) {
    {
      int rr = tid >> 2, c4 = (tid & 3) << 2;
      const float* ap = A + (size_t)(m0 + rr) * 512 + (k0 + c4);
      float4 av = *(const float4*)ap;
      As[(c4 + 0) * 65 + rr] = av.x; As[(c4 + 1) * 65 + rr] = av.y;
      As[(c4 + 2) * 65 + rr] = av.z; As[(c4 + 3) * 65 + rr] = av.w;
    }
    {
      int rr = tid >> 2, c4 = (tid & 3) << 2;
      const float* bp = B + (size_t)(n0 - base + rr) * 512 + (k0 + c4);
      float4 bv = *(const float4*)bp;
      Bs[(c4 + 0) * 65 + rr] = bv.x; Bs[(c4 + 1) * 65 + rr] = bv.y;
      Bs[(c4 + 2) * 65 + rr] = bv.z; Bs[(c4 + 3) * 65 + rr] = bv.w;
    }
    __syncthreads();
    #pragma unroll
    for (int k = 0; k < 16; ++k) {
      float av[4], bv[4];
      #pragma unroll
      for (int i = 0; i < 4; ++i) av[i] = As[k * 65 + ty * 4 + i];
      #pragma unroll
      for (int j = 0; j < 4; ++j) bv[j] = Bs[k * 65 + tx * 4 + j];
      #pragma unroll
      for (int i = 0; i < 4; ++i)
        #pragma unroll
        for (int j = 0; j < 4; ++j)
          acc[i][j] = fmaf(av[i], bv[j], acc[i][j]);
    }
    __syncthreads();
  }
  #pragma unroll
  for (int i = 0; i < 4; ++i) {
    int m = m0 + ty * 4 + i;
    #pragma unroll
    for (int j = 0; j < 4; ++j) {
      int n = n0 + tx * 4 + j;
      float v = acc[i][j] + bias[n - base];
      if (n < 1024) v = (v > 0.f) ? (v + 1.f) : __expf(v);
      C[(size_t)m * ldc + (n - base)] = v;
    }
  }
}

// ---------- flag helpers (relaxed agent ops only — no cache maintenance) ----------
__device__ __forceinline__ void post_flag(unsigned* flags, int w, unsigned v) {
  __hip_atomic_store(flags + (size_t)w * FLAG_STRIDE, v, __ATOMIC_RELAXED,
                     __HIP_MEMORY_SCOPE_AGENT);
}
__device__ __forceinline__ void poll64(const unsigned* flags, unsigned tgt, int lane) {
  const unsigned* p = flags + (size_t)lane * FLAG_STRIDE;
  while (__hip_atomic_load(p, __ATOMIC_RELAXED, __HIP_MEMORY_SCOPE_AGENT) < tgt)
    __builtin_amdgcn_s_sleep(1);
}

// ---------- fused two-layer pipelined GRU, register-resident weights ----------
// 128 WGs: 0..63 layer1 (fast), 64..127 layer2 (slow, lags 1 round).
// Round: wave0 polls dep A then stages h into LDS; wave1 polls dep B (stages
// h_s for L2). sync -> compute (r<24, weights in VGPRs) -> sync -> gate
// (wave0 lanes<16, sc1 h stores) -> wave0-local s_waitcnt(0) -> relaxed post.
// 2 __syncthreads per round (3rd removed: consumers' staging waves poll flag
// sets that include their OWN WG's flag, which is posted only after the gate,
// so LDS reuse is ordered without a block barrier).
__global__ __launch_bounds__(256, 1) void gru2_kernel(
    const float* __restrict__ gi,       // gi_f [1024][1536]
    const float* __restrict__ fwhh, const float* __restrict__ fbhh,
    const float* __restrict__ h0f,
    const float* __restrict__ swih, const float* __restrict__ sbih,
    const float* __restrict__ swhh, const float* __restrict__ sbhh,
    const float* __restrict__ h0s,
    float* __restrict__ pf_out,         // COMB cols [0,512), ld 2048
    float* __restrict__ ps_out,         // PS, ld 512
    float* __restrict__ hfT, float* __restrict__ hsT,
    float* __restrict__ ring,           // [4][1024]
    float* __restrict__ hsbuf,          // [2][1024]
    unsigned* __restrict__ flagsA, unsigned* __restrict__ flagsB) {
  __shared__ __attribute__((aligned(16))) float hl[1024];   // own-layer h
  __shared__ __attribute__((aligned(16))) float hfs[1024];  // p_f input (L2)
  __shared__ float P[48];
  __shared__ float Q[48];
  __shared__ float bl[24];
  __shared__ float bi[24];
  int tid = threadIdx.x, wg = blockIdx.x;
  bool L1 = wg < L_WGS;
  int j0 = (wg & (L_WGS - 1)) * UNITS;
  int part = tid & 7, r = tid >> 3;    // r in 0..31; active r<24
  int g = r >> 3, u = r & 7;           // gate, unit
  int wave = tid >> 6, lane = tid & 63;
  const float* whh = L1 ? fwhh : swhh;
  const float* bhh = L1 ? fbhh : sbhh;

  float4 wh[16], wi[16];
  if (r < 24) {
    const float* wp = whh + (size_t)(g * 512 + j0 + u) * 512 + part * 4;
    #pragma unroll
    for (int i = 0; i < 16; ++i) wh[i] = *(const float4*)(wp + i * 32);
    if (!L1) {
      const float* wp2 = swih + (size_t)(g * 512 + j0 + u) * 512 + part * 4;
      #pragma unroll
      for (int i = 0; i < 16; ++i) wi[i] = *(const float4*)(wp2 + i * 32);
    }
  }
  if (tid < 24) {
    bl[tid] = bhh[(tid >> 3) * 512 + j0 + (tid & 7)];
    if (!L1) bi[tid] = sbih[(tid >> 3) * 512 + j0 + (tid & 7)];
  }

  unsigned long long* hlq = (unsigned long long*)hl;
  unsigned long long* hfq = (unsigned long long*)hfs;
  const float4* h4 = (const float4*)hl;
  const float4* f4v = (const float4*)hfs;

  if (L1) {
    for (int t = 0; t < 512; ++t) {
      float i_r = 0.f, i_z = 0.f, i_n = 0.f;
      if (tid < 16) {   // issue gi loads early (in flight during poll)
        int b = tid >> 3, jl = tid & 7;
        const float* girow = gi + (size_t)(b * 512 + t) * 1536 + j0 + jl;
        i_r = girow[0]; i_z = girow[512]; i_n = girow[1024];
      }
      if (wave == 0) {
        if (t > 0) poll64(flagsA, (unsigned)t, lane);
        unsigned long long v[8];
        if (t == 0) {
          const unsigned long long* s8 = (const unsigned long long*)h0f;
          #pragma unroll
          for (int k = 0; k < 8; ++k) v[k] = s8[k * 64 + lane];
        } else {
          const unsigned long long* s8 =
              (const unsigned long long*)(ring + ((t - 1) & 3) * 1024);
          #pragma unroll
          for (int k = 0; k < 8; ++k)
            v[k] = __hip_atomic_load(s8 + k * 64 + lane, __ATOMIC_RELAXED,
                                     __HIP_MEMORY_SCOPE_AGENT);
        }
        #pragma unroll
        for (int k = 0; k < 8; ++k) hlq[k * 64 + lane] = v[k];
      } else if (wave == 1) {
        if (t >= 4) poll64(flagsB, (unsigned)(t - 3), lane);   // ring slot free
      }
      __syncthreads();
      if (r < 24) {
        float a0 = 0.f, a1 = 0.f;
        #pragma unroll
        for (int i = 0; i < 16; ++i) {
          float4 w = wh[i];
          float4 x0 = h4[i * 8 + part];
          float4 x1 = h4[128 + i * 8 + part];
          a0 += w.x * x0.x + w.y * x0.y + w.z * x0.z + w.w * x0.w;
          a1 += w.x * x1.x + w.y * x1.y + w.z * x1.z + w.w * x1.w;
        }
        a0 += __shfl_xor(a0, 1); a0 += __shfl_xor(a0, 2); a0 += __shfl_xor(a0, 4);
        a1 += __shfl_xor(a1, 1); a1 += __shfl_xor(a1, 2); a1 += __shfl_xor(a1, 4);
        if (part == 0) { P[r] = a0; P[24 + r] = a1; }
      }
      __syncthreads();
      if (tid < 16) {
        int b = tid >> 3, u2 = tid & 7, j = j0 + u2;
        float gh_r = P[b * 24 + u2] + bl[u2];
        float gh_z = P[b * 24 + 8 + u2] + bl[8 + u2];
        float gh_n = P[b * 24 + 16 + u2] + bl[16 + u2];
        float hold = hl[b * 512 + j];
        float rg = 1.0f / (1.0f + __expf(-(i_r + gh_r)));
        float zg = 1.0f / (1.0f + __expf(-(i_z + gh_z)));
        float ng = tanhf(i_n + rg * gh_n);
        float hnew = (1.0f - zg) * ng + zg * hold;
        __hip_atomic_store(ring + (size_t)(t & 3) * 1024 + b * 512 + j, hnew,
                           __ATOMIC_RELAXED, __HIP_MEMORY_SCOPE_AGENT);
        pf_out[(size_t)(b * 512 + t) * 2048 + j] = hnew;
        if (t == 511) hfT[b * 512 + j] = hnew;
      }
      if (tid == 0) {                       // wave0-local drain, then post
        __builtin_amdgcn_s_waitcnt(0);
        post_flag(flagsA, wg, (unsigned)(t + 1));
      }
    }
  } else {
    for (int t2 = 0; t2 < 512; ++t2) {
      if (wave == 0) {
        poll64(flagsA, (unsigned)(t2 + 1), lane);   // p_f(t2) ready
        const unsigned long long* f8 =
            (const unsigned long long*)(ring + (t2 & 3) * 1024);
        unsigned long long v[8];
        #pragma unroll
        for (int k = 0; k < 8; ++k)
          v[k] = __hip_atomic_load(f8 + k * 64 + lane, __ATOMIC_RELAXED,
                                   __HIP_MEMORY_SCOPE_AGENT);
        #pragma unroll
        for (int k = 0; k < 8; ++k) hfq[k * 64 + lane] = v[k];
      } else if (wave == 1) {
        unsigned long long v[8];
        if (t2 == 0) {
          const unsigned long long* s8 = (const unsigned long long*)h0s;
          #pragma unroll
          for (int k = 0; k < 8; ++k) v[k] = s8[k * 64 + lane];
        } else {
          poll64(flagsB, (unsigned)t2, lane);       // h_s(t2-1) ready (incl. own WG)
          const unsigned long long* s8 =
              (const unsigned long long*)(hsbuf + ((t2 - 1) & 1) * 1024);
          #pragma unroll
          for (int k = 0; k < 8; ++k)
            v[k] = __hip_atomic_load(s8 + k * 64 + lane, __ATOMIC_RELAXED,
                                     __HIP_MEMORY_SCOPE_AGENT);
        }
        #pragma unroll
        for (int k = 0; k < 8; ++k) hlq[k * 64 + lane] = v[k];
      }
      __syncthreads();
      if (r < 24) {
        float a0 = 0.f, a1 = 0.f, c0 = 0.f, c1 = 0.f;
        #pragma unroll
        for (int i = 0; i < 16; ++i) {
          float4 w = wh[i];
          float4 x0 = h4[i * 8 + part];
          float4 x1 = h4[128 + i * 8 + part];
          a0 += w.x * x0.x + w.y * x0.y + w.z * x0.z + w.w * x0.w;
          a1 += w.x * x1.x + w.y * x1.y + w.z * x1.z + w.w * x1.w;
          float4 v = wi[i];
          float4 y0 = f4v[i * 8 + part];
          float4 y1 = f4v[128 + i * 8 + part];
          c0 += v.x * y0.x + v.y * y0.y + v.z * y0.z + v.w * y0.w;
          c1 += v.x * y1.x + v.y * y1.y + v.z * y1.z + v.w * y1.w;
        }
        a0 += __shfl_xor(a0, 1); a0 += __shfl_xor(a0, 2); a0 += __shfl_xor(a0, 4);
        a1 += __shfl_xor(a1, 1); a1 += __shfl_xor(a1, 2); a1 += __shfl_xor(a1, 4);
        c0 += __shfl_xor(c0, 1); c0 += __shfl_xor(c0, 2); c0 += __shfl_xor(c0, 4);
        c1 += __shfl_xor(c1, 1); c1 += __shfl_xor(c1, 2); c1 += __shfl_xor(c1, 4);
        if (part == 0) { P[r] = a0; P[24 + r] = a1; Q[r] = c0; Q[24 + r] = c1; }
      }
      __syncthreads();
      if (tid < 16) {
        int b = tid >> 3, u2 = tid & 7, j = j0 + u2;
        float i_r = Q[b * 24 + u2] + bi[u2];
        float i_z = Q[b * 24 + 8 + u2] + bi[8 + u2];
        float i_n = Q[b * 24 + 16 + u2] + bi[16 + u2];
        float gh_r = P[b * 24 + u2] + bl[u2];
        float gh_z = P[b * 24 + 8 + u2] + bl[8 + u2];
        float gh_n = P[b * 24 + 16 + u2] + bl[16 + u2];
        float hold = hl[b * 512 + j];
        float rg = 1.0f / (1.0f + __expf(-(i_r + gh_r)));
        float zg = 1.0f / (1.0f + __expf(-(i_z + gh_z)));
        float ng = tanhf(i_n + rg * gh_n);
        float hnew = (1.0f - zg) * ng + zg * hold;
        __hip_atomic_store(hsbuf + (size_t)(t2 & 1) * 1024 + b * 512 + j, hnew,
                           __ATOMIC_RELAXED, __HIP_MEMORY_SCOPE_AGENT);
        ps_out[(size_t)(b * 512 + t2) * 512 + j] = hnew;
        if (t2 == 511) hsT[b * 512 + j] = hnew;
      }
      if (tid == 0) {                       // wave0-local drain, then post
        __builtin_amdgcn_s_waitcnt(0);
        post_flag(flagsB, wg - L_WGS, (unsigned)(t2 + 1));
      }
    }
  }
}

// ---------- small kernels ----------
__global__ __launch_bounds__(256) void softmax_kernel(float* __restrict__ a) {
  int m = blockIdx.x, tid = threadIdx.x;
  float v = a[(size_t)m * 256 + tid];
  float mx = v;
  #pragma unroll
  for (int off = 32; off > 0; off >>= 1) mx = fmaxf(mx, __shfl_down(mx, off));
  __shared__ float r4[4];
  __shared__ float s4[4];
  if ((tid & 63) == 0) r4[tid >> 6] = mx;
  __syncthreads();
  mx = fmaxf(fmaxf(r4[0], r4[1]), fmaxf(r4[2], r4[3]));
  float e = __expf(v - mx);
  float s = e;
  #pragma unroll
  for (int off = 32; off > 0; off >>= 1) s += __shfl_down(s, off);
  if ((tid & 63) == 0) s4[tid >> 6] = s;
  __syncthreads();
  s = s4[0] + s4[1] + s4[2] + s4[3];
  a[(size_t)m * 256 + tid] = e / s;
}

__global__ __launch_bounds__(256) void ln_kernel(
    const float* __restrict__ src, const float* __restrict__ src2,
    float* __restrict__ dst, int ldd, int dcoff,
    const float* __restrict__ gv, const float* __restrict__ bv, int tanhFirst) {
  int m = blockIdx.x, tid = threadIdx.x;
  float x0 = src[(size_t)m * 512 + tid];
  float x1 = src[(size_t)m * 512 + 256 + tid];
  if (src2) { x0 += src2[(size_t)m * 512 + tid]; x1 += src2[(size_t)m * 512 + 256 + tid]; }
  if (tanhFirst) { x0 = tanhf(x0); x1 = tanhf(x1); }
  float s = x0 + x1, ss = x0 * x0 + x1 * x1;
  #pragma unroll
  for (int off = 32; off > 0; off >>= 1) { s += __shfl_down(s, off); ss += __shfl_down(ss, off); }
  __shared__ float rs[4], rss[4];
  if ((tid & 63) == 0) { rs[tid >> 6] = s; rss[tid >> 6] = ss; }
  __syncthreads();
  float st = rs[0] + rs[1] + rs[2] + rs[3];
  float sst = rss[0] + rss[1] + rss[2] + rss[3];
  float mean = st * (1.0f / 512.0f);
  float var = sst * (1.0f / 512.0f) - mean * mean;
  float inv = rsqrtf(var + 1e-5f);
  float y0 = (x0 - mean) * inv * gv[tid] + bv[tid];
  float y1 = (x1 - mean) * inv * gv[256 + tid] + bv[256 + tid];
  if (!tanhFirst) { y0 = tanhf(y0); y1 = tanhf(y1); }
  dst[(size_t)m * ldd + dcoff + tid] = y0;
  dst[(size_t)m * ldd + dcoff + 256 + tid] = y1;
}

// inv-norm vector only: swn[r] = 16 / max(||soma_r||, 1e-12)
__global__ __launch_bounds__(256) void swinv_kernel(const float* __restrict__ soma,
                                                    float* __restrict__ swn) {
  int r = blockIdx.x, tid = threadIdx.x;
  float x0 = soma[(size_t)r * 512 + tid];
  float x1 = soma[(size_t)r * 512 + 256 + tid];
  float ss = x0 * x0 + x1 * x1;
  #pragma unroll
  for (int off = 32; off > 0; off >>= 1) ss += __shfl_down(ss, off);
  __shared__ float r4[4];
  if ((tid & 63) == 0) r4[tid >> 6] = ss;
  __syncthreads();
  if (tid == 0) {
    float norm = fmaxf(sqrtf(r4[0] + r4[1] + r4[2] + r4[3]), 1e-12f);
    swn[r] = 16.0f / norm;
  }
}

// ---------- host ----------
extern "C" void kernel_launch(void* const* d_in, const int* in_sizes, int n_in,
                              void* d_out, int out_size, void* d_ws, size_t ws_size,
                              hipStream_t stream) {
  (void)in_sizes; (void)n_in; (void)out_size; (void)ws_size;
  float* W = (float*)d_ws;
  float* outf = (float*)d_out;
  // out layout (floats): logits[262144] | thought[524288] | hf1[1024] | hs1[1024]
  const int* x = (const int*)d_in[0];
  const float* soma = (const float*)d_in[3];

  hipMemsetAsync((char*)d_ws + (size_t)OFF_FLAGS * 4, 0, 16384, stream);
  hipMemsetAsync((char*)d_ws + (size_t)OFF_DEN * 4, 0, 4096, stream);

  // gi_f = embed-gather(soma,x) @ fast_wih^T + fast_bih
  gemm<<<dim3(24, 16), 256, 0, stream>>>(soma, 512, (const float*)d_in[4], 512,
      W + OFF_GI, 1536, 0, 512, (const float*)d_in[6], nullptr, nullptr, nullptr,
      1.f, 0, 0, x, nullptr, 0);

  // fused GRU1+GRU2 -> p_f (COMB cols [0,512)), p_s (PS), hf1/hs1 -> out
  gru2_kernel<<<2 * L_WGS, 256, 0, stream>>>(W + OFF_GI,
      (const float*)d_in[5], (const float*)d_in[7], (const float*)d_in[1],
      (const float*)d_in[8], (const float*)d_in[10],
      (const float*)d_in[9], (const float*)d_in[11], (const float*)d_in[2],
      W + OFF_COMB, W + OFF_PS, outf + 786432, outf + 787456,
      W + OFF_RING, W + OFF_HSB,
      (unsigned*)(W + OFF_FLAGS), (unsigned*)(W + OFF_FLAGS) + L_WGS * FLAG_STRIDE);

  // merged: qkv (elu+1 on q,k) -> QKV ; gate pre -> TMP ; hip query -> QH
  gemm3<<<dim3(40, 16), 256, 0, stream>>>(W + OFF_PS,
      (const float*)d_in[12], (const float*)d_in[13],
      (const float*)d_in[14], (const float*)d_in[15],
      (const float*)d_in[19], (const float*)d_in[20],
      W + OFF_QKV, W + OFF_TMP, W + OFF_QH);

  // scores = causal(q k^T) per batch, row-sums fused -> DEN
  gemm<<<dim3(8, 16), 256, 0, stream>>>(W + OFF_QKV, 1536, W + OFF_QKV + 512, 1536,
      W + OFF_SCORES, 512, 0, 512, nullptr, nullptr, nullptr, W + OFF_DEN,
      1.f, F_CAUSAL | F_ROWSUM, 512, nullptr, nullptr, 0);

  // l_mem = (scores @ v) / (den + 1e-6) -> combined cols [1024,1536)
  gemm<<<dim3(8, 16), 256, 0, stream>>>(W + OFF_SCORES, 512, W + OFF_QKV + 1024, 1536,
      W + OFF_COMB, 2048, 1024, 512, nullptr, W + OFF_DEN, nullptr, nullptr,
      1.f, F_NN | F_DIV, 512, nullptr, nullptr, 0);

  // intent = tanh(LN(gate pre)) -> combined cols [512,1024)
  ln_kernel<<<1024, 256, 0, stream>>>(W + OFF_TMP, nullptr, W + OFF_COMB, 2048, 512,
      (const float*)d_in[16], (const float*)d_in[17], 0);

  // hippocampus attention -> combined cols [1536,2048)   (attn1 frees QH for axon)
  gemm<<<dim3(4, 16), 256, 0, stream>>>(W + OFF_QH, 512, (const float*)d_in[18], 512,
      W + OFF_ATTN, 256, 0, 512, nullptr, nullptr, nullptr, nullptr,
      0.04419417382415922f, F_SCALE, 0, nullptr, nullptr, 0);
  softmax_kernel<<<1024, 256, 0, stream>>>(W + OFF_ATTN);
  gemm<<<dim3(8, 16), 256, 0, stream>>>(W + OFF_ATTN, 256, (const float*)d_in[18], 512,
      W + OFF_COMB, 2048, 1536, 256, nullptr, nullptr, nullptr, nullptr,
      1.f, F_NN, 0, nullptr, nullptr, 0);

  // axon split-K x2 (one 256-block launch): k<1024 -> TMP (+bias), k>=1024 -> QH
  gemm<<<dim3(8, 16, 2), 256, 0, stream>>>(W + OFF_COMB, 2048, (const float*)d_in[21], 2048,
      W + OFF_TMP, 512, 0, 1024, (const float*)d_in[22], nullptr, nullptr, nullptr,
      1.f, 0, 0, nullptr, W + OFF_QH, 1024);

  // thought = LN(tanh(TMP + QH)) -> out (fp32)
  ln_kernel<<<1024, 256, 0, stream>>>(W + OFF_TMP, W + OFF_QH, outf + 262144, 512, 0,
      (const float*)d_in[23], (const float*)d_in[24], 1);

  // logits = thought @ soma^T scaled by 16/||soma_n|| -> out (fp32)
  swinv_kernel<<<256, 256, 0, stream>>>(soma, W + OFF_SWN);
  gemm<<<dim3(4, 16), 256, 0, stream>>>(outf + 262144, 512, soma, 512,
      outf, 256, 0, 512, nullptr, nullptr, W + OFF_SWN, nullptr,
      1.f, 0, 0, nullptr, nullptr, 0);
}

// Round 12
// 2027.966 us; speedup vs baseline: 1.0784x; 1.0703x over previous
//
#include <hip/hip_runtime.h>
#include <cstddef>

// B=2 T=512 D=512 V=256 MEM=256 ; M = B*T = 1024
// All inputs fp32 (x is int32); all outputs fp32.
#define F_ELUQK 1
#define F_CAUSAL 2
#define F_DIV 4
#define F_NN 8
#define F_SCALE 16
#define F_ROWSUM 32
#define FLAG_STRIDE 32   // u32 units -> 128 B per WG flag line
#define L_WGS 64         // WGs per GRU layer
#define UNITS 8          // hidden units per WG

// ---------- ws layout (float units) ----------
enum : int {
  OFF_QH = 0,                          // [1024][512] hip query / axon K-chunk-1 acc
  OFF_GI = 524288,                     // [1024][1536]
  OFF_COMB = OFF_GI + 1572864,         // [1024][2048]  p_f | intent | l_mem | episodes
  OFF_PS = OFF_COMB + 2097152,         // [1024][512]
  OFF_QKV = OFF_PS + 524288,           // [1024][1536]  q(elu+1) | k(elu+1) | v
  OFF_SCORES = OFF_QKV + 1572864,      // [1024][512]
  OFF_DEN = OFF_SCORES + 524288,       // [1024]
  OFF_TMP = OFF_DEN + 1024,            // [1024][512]
  OFF_ATTN = OFF_TMP + 524288,         // [1024][256]
  OFF_SWN = OFF_ATTN + 262144,         // [256] 16/||soma_row||
  OFF_RING = OFF_SWN + 256,            // [4][1024]  h_f ring
  OFF_HSB = OFF_RING + 4096,           // [2][1024]  h_s double buffer
  OFF_FLAGS = OFF_HSB + 2048           // flagsA[64*32] | flagsB[64*32]  (16 KB)
};

// ---------- generic tiled GEMM:  C[m, coff+n] = sum_k A(m,k) * B(n,k)  (+epilogue) ----------
// xidx: embedding gather on A rows. blockIdx.z=1: shift A,B by kzoff, write Cz, no bias.
// F_ROWSUM: atomicAdd per-row sums of stored values into rsum (pre-zeroed).
__global__ __launch_bounds__(256) void gemm(
    const float* __restrict__ A, int lda, const float* __restrict__ B, int ldb,
    float* __restrict__ C, int ldc, int coff, int K,
    const float* __restrict__ bias, const float* __restrict__ den,
    const float* __restrict__ cscale, float* __restrict__ rsum,
    float scale, int flags, int bBatch, const int* __restrict__ xidx,
    float* __restrict__ Cz, int kzoff) {
  __shared__ float As[16 * 65];
  __shared__ float Bs[16 * 65];
  int tid = threadIdx.x;
  int n0 = blockIdx.x * 64, m0 = blockIdx.y * 64;
  if (blockIdx.z) { A += kzoff; B += kzoff; C = Cz; bias = nullptr; }
  int rowoff = (m0 >> 9) * bBatch;
  int tx = tid & 15, ty = tid >> 4;

  if ((flags & F_CAUSAL) && n0 > ((m0 & 511) + 63)) {
    #pragma unroll
    for (int i = 0; i < 4; ++i)
      #pragma unroll
      for (int j = 0; j < 4; ++j)
        C[(size_t)(m0 + ty * 4 + i) * ldc + coff + n0 + tx * 4 + j] = 0.f;
    return;
  }

  float acc[4][4] = {};
  for (int k0 = 0; k0 < K; k0 += 16) {
    {
      int rr = tid >> 2, c4 = (tid & 3) << 2;
      int arow = m0 + rr;
      const float* ap = xidx ? (A + (size_t)xidx[arow] * 512 + (k0 + c4))
                             : (A + (size_t)arow * lda + (k0 + c4));
      float4 av = *(const float4*)ap;
      As[(c4 + 0) * 65 + rr] = av.x;
      As[(c4 + 1) * 65 + rr] = av.y;
      As[(c4 + 2) * 65 + rr] = av.z;
      As[(c4 + 3) * 65 + rr] = av.w;
    }
    if (!(flags & F_NN)) {
      int rr = tid >> 2, c4 = (tid & 3) << 2;
      const float* bp = B + (size_t)(n0 + rr + rowoff) * ldb + (k0 + c4);
      float4 bv = *(const float4*)bp;
      Bs[(c4 + 0) * 65 + rr] = bv.x; Bs[(c4 + 1) * 65 + rr] = bv.y;
      Bs[(c4 + 2) * 65 + rr] = bv.z; Bs[(c4 + 3) * 65 + rr] = bv.w;
    } else {
      int kk = tid >> 4, n4 = (tid & 15) << 2;
      const float* bp = B + (size_t)(k0 + kk + rowoff) * ldb + (n0 + n4);
      float4 bv = *(const float4*)bp;
      Bs[kk * 65 + n4 + 0] = bv.x; Bs[kk * 65 + n4 + 1] = bv.y;
      Bs[kk * 65 + n4 + 2] = bv.z; Bs[kk * 65 + n4 + 3] = bv.w;
    }
    __syncthreads();
    #pragma unroll
    for (int k = 0; k < 16; ++k) {
      float av[4], bv[4];
      #pragma unroll
      for (int i = 0; i < 4; ++i) av[i] = As[k * 65 + ty * 4 + i];
      #pragma unroll
      for (int j = 0; j < 4; ++j) bv[j] = Bs[k * 65 + tx * 4 + j];
      #pragma unroll
      for (int i = 0; i < 4; ++i)
        #pragma unroll
        for (int j = 0; j < 4; ++j)
          acc[i][j] = fmaf(av[i], bv[j], acc[i][j]);
    }
    __syncthreads();
  }
  float rs[4] = {0.f, 0.f, 0.f, 0.f};
  #pragma unroll
  for (int i = 0; i < 4; ++i) {
    int m = m0 + ty * 4 + i;
    float dv = (flags & F_DIV) ? (1.0f / (den[m] + 1e-6f)) : 1.0f;
    #pragma unroll
    for (int j = 0; j < 4; ++j) {
      int n = n0 + tx * 4 + j;
      float v = acc[i][j];
      if (bias) v += bias[n];
      if (flags & F_ELUQK) { if (n < 1024) v = (v > 0.f) ? (v + 1.f) : __expf(v); }
      if (flags & F_CAUSAL) { if (n > (m & 511)) v = 0.f; }
      if (flags & F_SCALE) v *= scale;
      if (cscale) v *= cscale[coff + n];
      if (flags & F_DIV) v *= dv;
      C[(size_t)m * ldc + coff + n] = v;
      if (flags & F_ROWSUM) rs[i] += v;
    }
  }
  if (flags & F_ROWSUM) {
    #pragma unroll
    for (int i = 0; i < 4; ++i) {
      float s = rs[i];
      s += __shfl_xor(s, 1); s += __shfl_xor(s, 2);
      s += __shfl_xor(s, 4); s += __shfl_xor(s, 8);
      if (tx == 0) atomicAdd(rsum + (m0 + ty * 4 + i), s);
    }
  }
}

// ---------- merged qkv / gate / hip_q projections (A = PS, K=512, NT) ----------
__global__ __launch_bounds__(256) void gemm3(
    const float* __restrict__ A,
    const float* __restrict__ qkvw, const float* __restrict__ qkvb,
    const float* __restrict__ gatew, const float* __restrict__ gateb,
    const float* __restrict__ hipw, const float* __restrict__ hipb,
    float* __restrict__ QKV, float* __restrict__ TMP, float* __restrict__ QH) {
  __shared__ float As[16 * 65];
  __shared__ float Bs[16 * 65];
  int tid = threadIdx.x;
  int n0 = blockIdx.x * 64, m0 = blockIdx.y * 64;
  const float* B; const float* bias; float* C; int ldc, base;
  if (n0 < 1536) { B = qkvw; bias = qkvb; C = QKV; ldc = 1536; base = 0; }
  else if (n0 < 2048) { B = gatew; bias = gateb; C = TMP; ldc = 512; base = 1536; }
  else { B = hipw; bias = hipb; C = QH; ldc = 512; base = 2048; }
  int tx = tid & 15, ty = tid >> 4;
  float acc[4][4] = {};
  for (int k0 = 0; k0 < 512; k0 += 16) {
    {
      int rr = tid >> 2, c4 = (tid & 3) << 2;
      const float* ap = A + (size_t)(m0 + rr) * 512 + (k0 + c4);
      float4 av = *(const float4*)ap;
      As[(c4 + 0) * 65 + rr] = av.x; As[(c4 + 1) * 65 + rr] = av.y;
      As[(c4 + 2) * 65 + rr] = av.z; As[(c4 + 3) * 65 + rr] = av.w;
    }
    {
      int rr = tid >> 2, c4 = (tid & 3) << 2;
      const float* bp = B + (size_t)(n0 - base + rr) * 512 + (k0 + c4);
      float4 bv = *(const float4*)bp;
      Bs[(c4 + 0) * 65 + rr] = bv.x; Bs[(c4 + 1) * 65 + rr] = bv.y;
      Bs[(c4 + 2) * 65 + rr] = bv.z; Bs[(c4 + 3) * 65 + rr] = bv.w;
    }
    __syncthreads();
    #pragma unroll
    for (int k = 0; k < 16; ++k) {
      float av[4], bv[4];
      #pragma unroll
      for (int i = 0; i < 4; ++i) av[i] = As[k * 65 + ty * 4 + i];
      #pragma unroll
      for (int j = 0; j < 4; ++j) bv[j] = Bs[k * 65 + tx * 4 + j];
      #pragma unroll
      for (int i = 0; i < 4; ++i)
        #pragma unroll
        for (int j = 0; j < 4; ++j)
          acc[i][j] = fmaf(av[i], bv[j], acc[i][j]);
    }
    __syncthreads();
  }
  #pragma unroll
  for (int i = 0; i < 4; ++i) {
    int m = m0 + ty * 4 + i;
    #pragma unroll
    for (int j = 0; j < 4; ++j) {
      int n = n0 + tx * 4 + j;
      float v = acc[i][j] + bias[n - base];
      if (n < 1024) v = (v > 0.f) ? (v + 1.f) : __expf(v);
      C[(size_t)m * ldc + (n - base)] = v;
    }
  }
}

// ---------- flag helpers (relaxed agent ops only — no cache maintenance) ----------
__device__ __forceinline__ void post_flag(unsigned* flags, int w, unsigned v) {
  __hip_atomic_store(flags + (size_t)w * FLAG_STRIDE, v, __ATOMIC_RELAXED,
                     __HIP_MEMORY_SCOPE_AGENT);
}
__device__ __forceinline__ void poll64(const unsigned* flags, unsigned tgt, int lane) {
  const unsigned* p = flags + (size_t)lane * FLAG_STRIDE;
  while (__hip_atomic_load(p, __ATOMIC_RELAXED, __HIP_MEMORY_SCOPE_AGENT) < tgt)
    __builtin_amdgcn_s_sleep(1);
}

// ---------- fused two-layer pipelined GRU, register-resident weights ----------
// 128 WGs: 0..63 layer1 (fast), 64..127 layer2 (slow, lags 1 round).
// Round: wave0 polls dep A then stages h into LDS; wave1 polls dep B (stages
// h_s for L2). sync -> compute (r<24, weights in VGPRs) -> sync -> gate
// (wave0 lanes<16, sc1 h stores) -> sync (full-block: drains vmcnt AND keeps
// all 4 waves phase-aligned — measured best; wave0-local drain regressed) ->
// relaxed flag post.
__global__ __launch_bounds__(256, 1) void gru2_kernel(
    const float* __restrict__ gi,       // gi_f [1024][1536]
    const float* __restrict__ fwhh, const float* __restrict__ fbhh,
    const float* __restrict__ h0f,
    const float* __restrict__ swih, const float* __restrict__ sbih,
    const float* __restrict__ swhh, const float* __restrict__ sbhh,
    const float* __restrict__ h0s,
    float* __restrict__ pf_out,         // COMB cols [0,512), ld 2048
    float* __restrict__ ps_out,         // PS, ld 512
    float* __restrict__ hfT, float* __restrict__ hsT,
    float* __restrict__ ring,           // [4][1024]
    float* __restrict__ hsbuf,          // [2][1024]
    unsigned* __restrict__ flagsA, unsigned* __restrict__ flagsB) {
  __shared__ __attribute__((aligned(16))) float hl[1024];   // own-layer h
  __shared__ __attribute__((aligned(16))) float hfs[1024];  // p_f input (L2)
  __shared__ float P[48];
  __shared__ float Q[48];
  __shared__ float bl[24];
  __shared__ float bi[24];
  int tid = threadIdx.x, wg = blockIdx.x;
  bool L1 = wg < L_WGS;
  int j0 = (wg & (L_WGS - 1)) * UNITS;
  int part = tid & 7, r = tid >> 3;    // r in 0..31; active r<24
  int g = r >> 3, u = r & 7;           // gate, unit
  int wave = tid >> 6, lane = tid & 63;
  const float* whh = L1 ? fwhh : swhh;
  const float* bhh = L1 ? fbhh : sbhh;

  float4 wh[16], wi[16];
  if (r < 24) {
    const float* wp = whh + (size_t)(g * 512 + j0 + u) * 512 + part * 4;
    #pragma unroll
    for (int i = 0; i < 16; ++i) wh[i] = *(const float4*)(wp + i * 32);
    if (!L1) {
      const float* wp2 = swih + (size_t)(g * 512 + j0 + u) * 512 + part * 4;
      #pragma unroll
      for (int i = 0; i < 16; ++i) wi[i] = *(const float4*)(wp2 + i * 32);
    }
  }
  if (tid < 24) {
    bl[tid] = bhh[(tid >> 3) * 512 + j0 + (tid & 7)];
    if (!L1) bi[tid] = sbih[(tid >> 3) * 512 + j0 + (tid & 7)];
  }

  unsigned long long* hlq = (unsigned long long*)hl;
  unsigned long long* hfq = (unsigned long long*)hfs;
  const float4* h4 = (const float4*)hl;
  const float4* f4v = (const float4*)hfs;

  if (L1) {
    for (int t = 0; t < 512; ++t) {
      float i_r = 0.f, i_z = 0.f, i_n = 0.f;
      if (tid < 16) {   // issue gi loads early (in flight during poll)
        int b = tid >> 3, jl = tid & 7;
        const float* girow = gi + (size_t)(b * 512 + t) * 1536 + j0 + jl;
        i_r = girow[0]; i_z = girow[512]; i_n = girow[1024];
      }
      if (wave == 0) {
        if (t > 0) poll64(flagsA, (unsigned)t, lane);
        unsigned long long v[8];
        if (t == 0) {
          const unsigned long long* s8 = (const unsigned long long*)h0f;
          #pragma unroll
          for (int k = 0; k < 8; ++k) v[k] = s8[k * 64 + lane];
        } else {
          const unsigned long long* s8 =
              (const unsigned long long*)(ring + ((t - 1) & 3) * 1024);
          #pragma unroll
          for (int k = 0; k < 8; ++k)
            v[k] = __hip_atomic_load(s8 + k * 64 + lane, __ATOMIC_RELAXED,
                                     __HIP_MEMORY_SCOPE_AGENT);
        }
        #pragma unroll
        for (int k = 0; k < 8; ++k) hlq[k * 64 + lane] = v[k];
      } else if (wave == 1) {
        if (t >= 4) poll64(flagsB, (unsigned)(t - 3), lane);   // ring slot free
      }
      __syncthreads();
      if (r < 24) {
        float a0 = 0.f, a1 = 0.f;
        #pragma unroll
        for (int i = 0; i < 16; ++i) {
          float4 w = wh[i];
          float4 x0 = h4[i * 8 + part];
          float4 x1 = h4[128 + i * 8 + part];
          a0 += w.x * x0.x + w.y * x0.y + w.z * x0.z + w.w * x0.w;
          a1 += w.x * x1.x + w.y * x1.y + w.z * x1.z + w.w * x1.w;
        }
        a0 += __shfl_xor(a0, 1); a0 += __shfl_xor(a0, 2); a0 += __shfl_xor(a0, 4);
        a1 += __shfl_xor(a1, 1); a1 += __shfl_xor(a1, 2); a1 += __shfl_xor(a1, 4);
        if (part == 0) { P[r] = a0; P[24 + r] = a1; }
      }
      __syncthreads();
      if (tid < 16) {
        int b = tid >> 3, u2 = tid & 7, j = j0 + u2;
        float gh_r = P[b * 24 + u2] + bl[u2];
        float gh_z = P[b * 24 + 8 + u2] + bl[8 + u2];
        float gh_n = P[b * 24 + 16 + u2] + bl[16 + u2];
        float hold = hl[b * 512 + j];
        float rg = 1.0f / (1.0f + __expf(-(i_r + gh_r)));
        float zg = 1.0f / (1.0f + __expf(-(i_z + gh_z)));
        float ng = tanhf(i_n + rg * gh_n);
        float hnew = (1.0f - zg) * ng + zg * hold;
        __hip_atomic_store(ring + (size_t)(t & 3) * 1024 + b * 512 + j, hnew,
                           __ATOMIC_RELAXED, __HIP_MEMORY_SCOPE_AGENT);
        pf_out[(size_t)(b * 512 + t) * 2048 + j] = hnew;
        if (t == 511) hfT[b * 512 + j] = hnew;
      }
      __syncthreads();   // drains vmcnt + keeps waves phase-aligned
      if (tid == 0) post_flag(flagsA, wg, (unsigned)(t + 1));
    }
  } else {
    for (int t2 = 0; t2 < 512; ++t2) {
      if (wave == 0) {
        poll64(flagsA, (unsigned)(t2 + 1), lane);   // p_f(t2) ready
        const unsigned long long* f8 =
            (const unsigned long long*)(ring + (t2 & 3) * 1024);
        unsigned long long v[8];
        #pragma unroll
        for (int k = 0; k < 8; ++k)
          v[k] = __hip_atomic_load(f8 + k * 64 + lane, __ATOMIC_RELAXED,
                                   __HIP_MEMORY_SCOPE_AGENT);
        #pragma unroll
        for (int k = 0; k < 8; ++k) hfq[k * 64 + lane] = v[k];
      } else if (wave == 1) {
        unsigned long long v[8];
        if (t2 == 0) {
          const unsigned long long* s8 = (const unsigned long long*)h0s;
          #pragma unroll
          for (int k = 0; k < 8; ++k) v[k] = s8[k * 64 + lane];
        } else {
          poll64(flagsB, (unsigned)t2, lane);       // h_s(t2-1) ready
          const unsigned long long* s8 =
              (const unsigned long long*)(hsbuf + ((t2 - 1) & 1) * 1024);
          #pragma unroll
          for (int k = 0; k < 8; ++k)
            v[k] = __hip_atomic_load(s8 + k * 64 + lane, __ATOMIC_RELAXED,
                                     __HIP_MEMORY_SCOPE_AGENT);
        }
        #pragma unroll
        for (int k = 0; k < 8; ++k) hlq[k * 64 + lane] = v[k];
      }
      __syncthreads();
      if (r < 24) {
        float a0 = 0.f, a1 = 0.f, c0 = 0.f, c1 = 0.f;
        #pragma unroll
        for (int i = 0; i < 16; ++i) {
          float4 w = wh[i];
          float4 x0 = h4[i * 8 + part];
          float4 x1 = h4[128 + i * 8 + part];
          a0 += w.x * x0.x + w.y * x0.y + w.z * x0.z + w.w * x0.w;
          a1 += w.x * x1.x + w.y * x1.y + w.z * x1.z + w.w * x1.w;
          float4 v = wi[i];
          float4 y0 = f4v[i * 8 + part];
          float4 y1 = f4v[128 + i * 8 + part];
          c0 += v.x * y0.x + v.y * y0.y + v.z * y0.z + v.w * y0.w;
          c1 += v.x * y1.x + v.y * y1.y + v.z * y1.z + v.w * y1.w;
        }
        a0 += __shfl_xor(a0, 1); a0 += __shfl_xor(a0, 2); a0 += __shfl_xor(a0, 4);
        a1 += __shfl_xor(a1, 1); a1 += __shfl_xor(a1, 2); a1 += __shfl_xor(a1, 4);
        c0 += __shfl_xor(c0, 1); c0 += __shfl_xor(c0, 2); c0 += __shfl_xor(c0, 4);
        c1 += __shfl_xor(c1, 1); c1 += __shfl_xor(c1, 2); c1 += __shfl_xor(c1, 4);
        if (part == 0) { P[r] = a0; P[24 + r] = a1; Q[r] = c0; Q[24 + r] = c1; }
      }
      __syncthreads();
      if (tid < 16) {
        int b = tid >> 3, u2 = tid & 7, j = j0 + u2;
        float i_r = Q[b * 24 + u2] + bi[u2];
        float i_z = Q[b * 24 + 8 + u2] + bi[8 + u2];
        float i_n = Q[b * 24 + 16 + u2] + bi[16 + u2];
        float gh_r = P[b * 24 + u2] + bl[u2];
        float gh_z = P[b * 24 + 8 + u2] + bl[8 + u2];
        float gh_n = P[b * 24 + 16 + u2] + bl[16 + u2];
        float hold = hl[b * 512 + j];
        float rg = 1.0f / (1.0f + __expf(-(i_r + gh_r)));
        float zg = 1.0f / (1.0f + __expf(-(i_z + gh_z)));
        float ng = tanhf(i_n + rg * gh_n);
        float hnew = (1.0f - zg) * ng + zg * hold;
        __hip_atomic_store(hsbuf + (size_t)(t2 & 1) * 1024 + b * 512 + j, hnew,
                           __ATOMIC_RELAXED, __HIP_MEMORY_SCOPE_AGENT);
        ps_out[(size_t)(b * 512 + t2) * 512 + j] = hnew;
        if (t2 == 511) hsT[b * 512 + j] = hnew;
      }
      __syncthreads();   // drains vmcnt + keeps waves phase-aligned
      if (tid == 0) post_flag(flagsB, wg - L_WGS, (unsigned)(t2 + 1));
    }
  }
}

// ---------- small kernels ----------
__global__ __launch_bounds__(256) void softmax_kernel(float* __restrict__ a) {
  int m = blockIdx.x, tid = threadIdx.x;
  float v = a[(size_t)m * 256 + tid];
  float mx = v;
  #pragma unroll
  for (int off = 32; off > 0; off >>= 1) mx = fmaxf(mx, __shfl_down(mx, off));
  __shared__ float r4[4];
  __shared__ float s4[4];
  if ((tid & 63) == 0) r4[tid >> 6] = mx;
  __syncthreads();
  mx = fmaxf(fmaxf(r4[0], r4[1]), fmaxf(r4[2], r4[3]));
  float e = __expf(v - mx);
  float s = e;
  #pragma unroll
  for (int off = 32; off > 0; off >>= 1) s += __shfl_down(s, off);
  if ((tid & 63) == 0) s4[tid >> 6] = s;
  __syncthreads();
  s = s4[0] + s4[1] + s4[2] + s4[3];
  a[(size_t)m * 256 + tid] = e / s;
}

__global__ __launch_bounds__(256) void ln_kernel(
    const float* __restrict__ src, const float* __restrict__ src2,
    float* __restrict__ dst, int ldd, int dcoff,
    const float* __restrict__ gv, const float* __restrict__ bv, int tanhFirst) {
  int m = blockIdx.x, tid = threadIdx.x;
  float x0 = src[(size_t)m * 512 + tid];
  float x1 = src[(size_t)m * 512 + 256 + tid];
  if (src2) { x0 += src2[(size_t)m * 512 + tid]; x1 += src2[(size_t)m * 512 + 256 + tid]; }
  if (tanhFirst) { x0 = tanhf(x0); x1 = tanhf(x1); }
  float s = x0 + x1, ss = x0 * x0 + x1 * x1;
  #pragma unroll
  for (int off = 32; off > 0; off >>= 1) { s += __shfl_down(s, off); ss += __shfl_down(ss, off); }
  __shared__ float rs[4], rss[4];
  if ((tid & 63) == 0) { rs[tid >> 6] = s; rss[tid >> 6] = ss; }
  __syncthreads();
  float st = rs[0] + rs[1] + rs[2] + rs[3];
  float sst = rss[0] + rss[1] + rss[2] + rss[3];
  float mean = st * (1.0f / 512.0f);
  float var = sst * (1.0f / 512.0f) - mean * mean;
  float inv = rsqrtf(var + 1e-5f);
  float y0 = (x0 - mean) * inv * gv[tid] + bv[tid];
  float y1 = (x1 - mean) * inv * gv[256 + tid] + bv[256 + tid];
  if (!tanhFirst) { y0 = tanhf(y0); y1 = tanhf(y1); }
  dst[(size_t)m * ldd + dcoff + tid] = y0;
  dst[(size_t)m * ldd + dcoff + 256 + tid] = y1;
}

// inv-norm vector only: swn[r] = 16 / max(||soma_r||, 1e-12)
__global__ __launch_bounds__(256) void swinv_kernel(const float* __restrict__ soma,
                                                    float* __restrict__ swn) {
  int r = blockIdx.x, tid = threadIdx.x;
  float x0 = soma[(size_t)r * 512 + tid];
  float x1 = soma[(size_t)r * 512 + 256 + tid];
  float ss = x0 * x0 + x1 * x1;
  #pragma unroll
  for (int off = 32; off > 0; off >>= 1) ss += __shfl_down(ss, off);
  __shared__ float r4[4];
  if ((tid & 63) == 0) r4[tid >> 6] = ss;
  __syncthreads();
  if (tid == 0) {
    float norm = fmaxf(sqrtf(r4[0] + r4[1] + r4[2] + r4[3]), 1e-12f);
    swn[r] = 16.0f / norm;
  }
}

// ---------- host ----------
extern "C" void kernel_launch(void* const* d_in, const int* in_sizes, int n_in,
                              void* d_out, int out_size, void* d_ws, size_t ws_size,
                              hipStream_t stream) {
  (void)in_sizes; (void)n_in; (void)out_size; (void)ws_size;
  float* W = (float*)d_ws;
  float* outf = (float*)d_out;
  // out layout (floats): logits[262144] | thought[524288] | hf1[1024] | hs1[1024]
  const int* x = (const int*)d_in[0];
  const float* soma = (const float*)d_in[3];

  hipMemsetAsync((char*)d_ws + (size_t)OFF_FLAGS * 4, 0, 16384, stream);
  hipMemsetAsync((char*)d_ws + (size_t)OFF_DEN * 4, 0, 4096, stream);

  // gi_f = embed-gather(soma,x) @ fast_wih^T + fast_bih
  gemm<<<dim3(24, 16), 256, 0, stream>>>(soma, 512, (const float*)d_in[4], 512,
      W + OFF_GI, 1536, 0, 512, (const float*)d_in[6], nullptr, nullptr, nullptr,
      1.f, 0, 0, x, nullptr, 0);

  // fused GRU1+GRU2 -> p_f (COMB cols [0,512)), p_s (PS), hf1/hs1 -> out
  gru2_kernel<<<2 * L_WGS, 256, 0, stream>>>(W + OFF_GI,
      (const float*)d_in[5], (const float*)d_in[7], (const float*)d_in[1],
      (const float*)d_in[8], (const float*)d_in[10],
      (const float*)d_in[9], (const float*)d_in[11], (const float*)d_in[2],
      W + OFF_COMB, W + OFF_PS, outf + 786432, outf + 787456,
      W + OFF_RING, W + OFF_HSB,
      (unsigned*)(W + OFF_FLAGS), (unsigned*)(W + OFF_FLAGS) + L_WGS * FLAG_STRIDE);

  // merged: qkv (elu+1 on q,k) -> QKV ; gate pre -> TMP ; hip query -> QH
  gemm3<<<dim3(40, 16), 256, 0, stream>>>(W + OFF_PS,
      (const float*)d_in[12], (const float*)d_in[13],
      (const float*)d_in[14], (const float*)d_in[15],
      (const float*)d_in[19], (const float*)d_in[20],
      W + OFF_QKV, W + OFF_TMP, W + OFF_QH);

  // scores = causal(q k^T) per batch, row-sums fused -> DEN
  gemm<<<dim3(8, 16), 256, 0, stream>>>(W + OFF_QKV, 1536, W + OFF_QKV + 512, 1536,
      W + OFF_SCORES, 512, 0, 512, nullptr, nullptr, nullptr, W + OFF_DEN,
      1.f, F_CAUSAL | F_ROWSUM, 512, nullptr, nullptr, 0);

  // l_mem = (scores @ v) / (den + 1e-6) -> combined cols [1024,1536)
  gemm<<<dim3(8, 16), 256, 0, stream>>>(W + OFF_SCORES, 512, W + OFF_QKV + 1024, 1536,
      W + OFF_COMB, 2048, 1024, 512, nullptr, W + OFF_DEN, nullptr, nullptr,
      1.f, F_NN | F_DIV, 512, nullptr, nullptr, 0);

  // intent = tanh(LN(gate pre)) -> combined cols [512,1024)
  ln_kernel<<<1024, 256, 0, stream>>>(W + OFF_TMP, nullptr, W + OFF_COMB, 2048, 512,
      (const float*)d_in[16], (const float*)d_in[17], 0);

  // hippocampus attention -> combined cols [1536,2048)
  gemm<<<dim3(4, 16), 256, 0, stream>>>(W + OFF_QH, 512, (const float*)d_in[18], 512,
      W + OFF_ATTN, 256, 0, 512, nullptr, nullptr, nullptr, nullptr,
      0.04419417382415922f, F_SCALE, 0, nullptr, nullptr, 0);
  softmax_kernel<<<1024, 256, 0, stream>>>(W + OFF_ATTN);
  gemm<<<dim3(8, 16), 256, 0, stream>>>(W + OFF_ATTN, 256, (const float*)d_in[18], 512,
      W + OFF_COMB, 2048, 1536, 256, nullptr, nullptr, nullptr, nullptr,
      1.f, F_NN, 0, nullptr, nullptr, 0);

  // axon split-K x2 (one 256-block launch): k<1024 -> TMP (+bias), k>=1024 -> QH
  gemm<<<dim3(8, 16, 2), 256, 0, stream>>>(W + OFF_COMB, 2048, (const float*)d_in[21], 2048,
      W + OFF_TMP, 512, 0, 1024, (const float*)d_in[22], nullptr, nullptr, nullptr,
      1.f, 0, 0, nullptr, W + OFF_QH, 1024);

  // thought = LN(tanh(TMP + QH)) -> out (fp32)
  ln_kernel<<<1024, 256, 0, stream>>>(W + OFF_TMP, W + OFF_QH, outf + 262144, 512, 0,
      (const float*)d_in[23], (const float*)d_in[24], 1);

  // logits = thought @ soma^T scaled by 16/||soma_n|| -> out (fp32)
  swinv_kernel<<<256, 256, 0, stream>>>(soma, W + OFF_SWN);
  gemm<<<dim3(4, 16), 256, 0, stream>>>(outf + 262144, 512, soma, 512,
      outf, 256, 0, 512, nullptr, nullptr, W + OFF_SWN, nullptr,
      1.f, 0, 0, nullptr, nullptr, 0);
}

// Round 13
// 2024.496 us; speedup vs baseline: 1.0802x; 1.0017x over previous
//
#include <hip/hip_runtime.h>
#include <cstddef>

// B=2 T=512 D=512 V=256 MEM=256 ; M = B*T = 1024
// All inputs fp32 (x is int32); all outputs fp32.
#define F_ELUQK 1
#define F_CAUSAL 2
#define F_DIV 4
#define F_NN 8
#define F_SCALE 16
#define F_ROWSUM 32
#define FLAG_STRIDE 32   // u32 units -> 128 B per WG flag line
#define L_WGS 64         // WGs per GRU layer
#define UNITS 8          // hidden units per WG

// ---------- ws layout (float units) ----------
enum : int {
  OFF_QH = 0,                          // [1024][512] hip query / axon K-chunk-1 acc
  OFF_COMB = 524288,                   // [1024][2048]  p_f | intent | l_mem | episodes
  OFF_PS = OFF_COMB + 2097152,         // [1024][512]
  OFF_QKV = OFF_PS + 524288,           // [1024][1536]  q(elu+1) | k(elu+1) | v
  OFF_SCORES = OFF_QKV + 1572864,      // [1024][512]
  OFF_DEN = OFF_SCORES + 524288,       // [1024]
  OFF_TMP = OFF_DEN + 1024,            // [1024][512]
  OFF_ATTN = OFF_TMP + 524288,         // [1024][256]
  OFF_SWN = OFF_ATTN + 262144,         // [256] 16/||soma_row||
  OFF_RING = OFF_SWN + 256,            // [4][1024]  h_f ring
  OFF_HSB = OFF_RING + 4096,           // [2][1024]  h_s double buffer
  OFF_FLAGS = OFF_HSB + 2048           // flagsA[64*32] | flagsB[64*32]  (16 KB)
};

// ---------- generic tiled GEMM:  C[m, coff+n] = sum_k A(m,k) * B(n,k)  (+epilogue) ----------
__global__ __launch_bounds__(256) void gemm(
    const float* __restrict__ A, int lda, const float* __restrict__ B, int ldb,
    float* __restrict__ C, int ldc, int coff, int K,
    const float* __restrict__ bias, const float* __restrict__ den,
    const float* __restrict__ cscale, float* __restrict__ rsum,
    float scale, int flags, int bBatch,
    float* __restrict__ Cz, int kzoff) {
  __shared__ float As[16 * 65];
  __shared__ float Bs[16 * 65];
  int tid = threadIdx.x;
  int n0 = blockIdx.x * 64, m0 = blockIdx.y * 64;
  if (blockIdx.z) { A += kzoff; B += kzoff; C = Cz; bias = nullptr; }
  int rowoff = (m0 >> 9) * bBatch;
  int tx = tid & 15, ty = tid >> 4;

  if ((flags & F_CAUSAL) && n0 > ((m0 & 511) + 63)) {
    #pragma unroll
    for (int i = 0; i < 4; ++i)
      #pragma unroll
      for (int j = 0; j < 4; ++j)
        C[(size_t)(m0 + ty * 4 + i) * ldc + coff + n0 + tx * 4 + j] = 0.f;
    return;
  }

  float acc[4][4] = {};
  for (int k0 = 0; k0 < K; k0 += 16) {
    {
      int rr = tid >> 2, c4 = (tid & 3) << 2;
      const float* ap = A + (size_t)(m0 + rr) * lda + (k0 + c4);
      float4 av = *(const float4*)ap;
      As[(c4 + 0) * 65 + rr] = av.x;
      As[(c4 + 1) * 65 + rr] = av.y;
      As[(c4 + 2) * 65 + rr] = av.z;
      As[(c4 + 3) * 65 + rr] = av.w;
    }
    if (!(flags & F_NN)) {
      int rr = tid >> 2, c4 = (tid & 3) << 2;
      const float* bp = B + (size_t)(n0 + rr + rowoff) * ldb + (k0 + c4);
      float4 bv = *(const float4*)bp;
      Bs[(c4 + 0) * 65 + rr] = bv.x; Bs[(c4 + 1) * 65 + rr] = bv.y;
      Bs[(c4 + 2) * 65 + rr] = bv.z; Bs[(c4 + 3) * 65 + rr] = bv.w;
    } else {
      int kk = tid >> 4, n4 = (tid & 15) << 2;
      const float* bp = B + (size_t)(k0 + kk + rowoff) * ldb + (n0 + n4);
      float4 bv = *(const float4*)bp;
      Bs[kk * 65 + n4 + 0] = bv.x; Bs[kk * 65 + n4 + 1] = bv.y;
      Bs[kk * 65 + n4 + 2] = bv.z; Bs[kk * 65 + n4 + 3] = bv.w;
    }
    __syncthreads();
    #pragma unroll
    for (int k = 0; k < 16; ++k) {
      float av[4], bv[4];
      #pragma unroll
      for (int i = 0; i < 4; ++i) av[i] = As[k * 65 + ty * 4 + i];
      #pragma unroll
      for (int j = 0; j < 4; ++j) bv[j] = Bs[k * 65 + tx * 4 + j];
      #pragma unroll
      for (int i = 0; i < 4; ++i)
        #pragma unroll
        for (int j = 0; j < 4; ++j)
          acc[i][j] = fmaf(av[i], bv[j], acc[i][j]);
    }
    __syncthreads();
  }
  float rs[4] = {0.f, 0.f, 0.f, 0.f};
  #pragma unroll
  for (int i = 0; i < 4; ++i) {
    int m = m0 + ty * 4 + i;
    float dv = (flags & F_DIV) ? (1.0f / (den[m] + 1e-6f)) : 1.0f;
    #pragma unroll
    for (int j = 0; j < 4; ++j) {
      int n = n0 + tx * 4 + j;
      float v = acc[i][j];
      if (bias) v += bias[n];
      if (flags & F_ELUQK) { if (n < 1024) v = (v > 0.f) ? (v + 1.f) : __expf(v); }
      if (flags & F_CAUSAL) { if (n > (m & 511)) v = 0.f; }
      if (flags & F_SCALE) v *= scale;
      if (cscale) v *= cscale[coff + n];
      if (flags & F_DIV) v *= dv;
      C[(size_t)m * ldc + coff + n] = v;
      if (flags & F_ROWSUM) rs[i] += v;
    }
  }
  if (flags & F_ROWSUM) {
    #pragma unroll
    for (int i = 0; i < 4; ++i) {
      float s = rs[i];
      s += __shfl_xor(s, 1); s += __shfl_xor(s, 2);
      s += __shfl_xor(s, 4); s += __shfl_xor(s, 8);
      if (tx == 0) atomicAdd(rsum + (m0 + ty * 4 + i), s);
    }
  }
}

// ---------- merged qkv / gate / hip_q projections (A = PS, K=512, NT) ----------
__global__ __launch_bounds__(256) void gemm3(
    const float* __restrict__ A,
    const float* __restrict__ qkvw, const float* __restrict__ qkvb,
    const float* __restrict__ gatew, const float* __restrict__ gateb,
    const float* __restrict__ hipw, const float* __restrict__ hipb,
    float* __restrict__ QKV, float* __restrict__ TMP, float* __restrict__ QH) {
  __shared__ float As[16 * 65];
  __shared__ float Bs[16 * 65];
  int tid = threadIdx.x;
  int n0 = blockIdx.x * 64, m0 = blockIdx.y * 64;
  const float* B; const float* bias; float* C; int ldc, base;
  if (n0 < 1536) { B = qkvw; bias = qkvb; C = QKV; ldc = 1536; base = 0; }
  else if (n0 < 2048) { B = gatew; bias = gateb; C = TMP; ldc = 512; base = 1536; }
  else { B = hipw; bias = hipb; C = QH; ldc = 512; base = 2048; }
  int tx = tid & 15, ty = tid >> 4;
  float acc[4][4] = {};
  for (int k0 = 0; k0 < 512; k0 += 16) {
    {
      int rr = tid >> 2, c4 = (tid & 3) << 2;
      const float* ap = A + (size_t)(m0 + rr) * 512 + (k0 + c4);
      float4 av = *(const float4*)ap;
      As[(c4 + 0) * 65 + rr] = av.x; As[(c4 + 1) * 65 + rr] = av.y;
      As[(c4 + 2) * 65 + rr] = av.z; As[(c4 + 3) * 65 + rr] = av.w;
    }
    {
      int rr = tid >> 2, c4 = (tid & 3) << 2;
      const float* bp = B + (size_t)(n0 - base + rr) * 512 + (k0 + c4);
      float4 bv = *(const float4*)bp;
      Bs[(c4 + 0) * 65 + rr] = bv.x; Bs[(c4 + 1) * 65 + rr] = bv.y;
      Bs[(c4 + 2) * 65 + rr] = bv.z; Bs[(c4 + 3) * 65 + rr] = bv.w;
    }
    __syncthreads();
    #pragma unroll
    for (int k = 0; k < 16; ++k) {
      float av[4], bv[4];
      #pragma unroll
      for (int i = 0; i < 4; ++i) av[i] = As[k * 65 + ty * 4 + i];
      #pragma unroll
      for (int j = 0; j < 4; ++j) bv[j] = Bs[k * 65 + tx * 4 + j];
      #pragma unroll
      for (int i = 0; i < 4; ++i)
        #pragma unroll
        for (int j = 0; j < 4; ++j)
          acc[i][j] = fmaf(av[i], bv[j], acc[i][j]);
    }
    __syncthreads();
  }
  #pragma unroll
  for (int i = 0; i < 4; ++i) {
    int m = m0 + ty * 4 + i;
    #pragma unroll
    for (int j = 0; j < 4; ++j) {
      int n = n0 + tx * 4 + j;
      float v = acc[i][j] + bias[n - base];
      if (n < 1024) v = (v > 0.f) ? (v + 1.f) : __expf(v);
      C[(size_t)m * ldc + (n - base)] = v;
    }
  }
}

// ---------- flag helpers (relaxed agent ops only — no cache maintenance) ----------
__device__ __forceinline__ void post_flag(unsigned* flags, int w, unsigned v) {
  __hip_atomic_store(flags + (size_t)w * FLAG_STRIDE, v, __ATOMIC_RELAXED,
                     __HIP_MEMORY_SCOPE_AGENT);
}
__device__ __forceinline__ void poll64(const unsigned* flags, unsigned tgt, int lane) {
  const unsigned* p = flags + (size_t)lane * FLAG_STRIDE;
  while (__hip_atomic_load(p, __ATOMIC_RELAXED, __HIP_MEMORY_SCOPE_AGENT) < tgt)
    __builtin_amdgcn_s_sleep(1);
}

// ---------- fused two-layer pipelined GRU, register-resident weights ----------
// 128 WGs: 0..63 layer1 (fast), 64..127 layer2 (slow, lags 1 round).
// BOTH layers: two 48-row dots per round (gh = whh.h  and  gi = wih.input).
// L1's input s_in(t) = soma[x[t]] has NO recurrent dep -> waves 2/3 prefetch it
// into an LDS double buffer one round ahead (the standalone gi_f GEMM is gone).
// L2's input p_f(t) arrives via the sc1 ring (polled).
// Round: wave0 polls dep A + stages; wave1 polls dep B (+ stages h_s for L2);
// waves2/3 (L1) prefetch s_in(t+1). sync -> compute -> sync -> gate -> sync
// (full-block: drains vmcnt + phase-aligns waves; measured best) -> post.
__global__ __launch_bounds__(256, 1) void gru2_kernel(
    const float* __restrict__ soma, const int* __restrict__ x,
    const float* __restrict__ fwih, const float* __restrict__ fbih,
    const float* __restrict__ fwhh, const float* __restrict__ fbhh,
    const float* __restrict__ h0f,
    const float* __restrict__ swih, const float* __restrict__ sbih,
    const float* __restrict__ swhh, const float* __restrict__ sbhh,
    const float* __restrict__ h0s,
    float* __restrict__ pf_out,         // COMB cols [0,512), ld 2048
    float* __restrict__ ps_out,         // PS, ld 512
    float* __restrict__ hfT, float* __restrict__ hsT,
    float* __restrict__ ring,           // [4][1024]
    float* __restrict__ hsbuf,          // [2][1024]
    unsigned* __restrict__ flagsA, unsigned* __restrict__ flagsB) {
  __shared__ __attribute__((aligned(16))) float hl[1024];    // own-layer h
  __shared__ __attribute__((aligned(16))) float inb[2048];   // input dbuf (s_in or p_f)
  __shared__ float P[48];
  __shared__ float Q[48];
  __shared__ float bl[24];
  __shared__ float bi[24];
  __shared__ int xl[1024];
  int tid = threadIdx.x, wg = blockIdx.x;
  bool L1 = wg < L_WGS;
  int j0 = (wg & (L_WGS - 1)) * UNITS;
  int part = tid & 7, r = tid >> 3;    // r in 0..31; active r<24
  int g = r >> 3, u = r & 7;           // gate, unit
  int wave = tid >> 6, lane = tid & 63;
  const float* whh = L1 ? fwhh : swhh;
  const float* bhh = L1 ? fbhh : sbhh;
  const float* wih = L1 ? fwih : swih;
  const float* bih = L1 ? fbih : sbih;

  float4 wh[16], wi[16];
  if (r < 24) {
    const float* wp = whh + (size_t)(g * 512 + j0 + u) * 512 + part * 4;
    #pragma unroll
    for (int i = 0; i < 16; ++i) wh[i] = *(const float4*)(wp + i * 32);
    const float* wp2 = wih + (size_t)(g * 512 + j0 + u) * 512 + part * 4;
    #pragma unroll
    for (int i = 0; i < 16; ++i) wi[i] = *(const float4*)(wp2 + i * 32);
  }
  if (tid < 24) {
    bl[tid] = bhh[(tid >> 3) * 512 + j0 + (tid & 7)];
    bi[tid] = bih[(tid >> 3) * 512 + j0 + (tid & 7)];
  }
  if (L1) {
    for (int q = tid; q < 1024; q += 256) xl[q] = x[q];
  }
  __syncthreads();

  unsigned long long* hlq = (unsigned long long*)hl;
  unsigned long long* inq = (unsigned long long*)inb;
  const float4* h4 = (const float4*)hl;

  if (L1) {
    for (int t = 0; t < 512; ++t) {
      if (wave == 0) {
        if (t > 0) poll64(flagsA, (unsigned)t, lane);
        unsigned long long v[8];
        if (t == 0) {
          const unsigned long long* s8 = (const unsigned long long*)h0f;
          #pragma unroll
          for (int k = 0; k < 8; ++k) v[k] = s8[k * 64 + lane];
        } else {
          const unsigned long long* s8 =
              (const unsigned long long*)(ring + ((t - 1) & 3) * 1024);
          #pragma unroll
          for (int k = 0; k < 8; ++k)
            v[k] = __hip_atomic_load(s8 + k * 64 + lane, __ATOMIC_RELAXED,
                                     __HIP_MEMORY_SCOPE_AGENT);
        }
        #pragma unroll
        for (int k = 0; k < 8; ++k) hlq[k * 64 + lane] = v[k];
      } else if (wave == 1) {
        if (t >= 4) poll64(flagsB, (unsigned)(t - 3), lane);   // ring slot free
      } else {
        int b = wave - 2;
        if (t == 0) {
          int row0 = xl[b * 512];
          const float4* sp = (const float4*)(soma + (size_t)row0 * 512);
          float4* dst = (float4*)(inb + b * 512);
          dst[lane * 2] = sp[lane * 2]; dst[lane * 2 + 1] = sp[lane * 2 + 1];
        }
        if (t + 1 < 512) {
          int row = xl[b * 512 + t + 1];
          const float4* sp = (const float4*)(soma + (size_t)row * 512);
          float4* dst = (float4*)(inb + ((t + 1) & 1) * 1024 + b * 512);
          dst[lane * 2] = sp[lane * 2]; dst[lane * 2 + 1] = sp[lane * 2 + 1];
        }
      }
      __syncthreads();
      if (r < 24) {
        const float4* f4v = (const float4*)(inb + (t & 1) * 1024);
        float a0 = 0.f, a1 = 0.f, c0 = 0.f, c1 = 0.f;
        #pragma unroll
        for (int i = 0; i < 16; ++i) {
          float4 w = wh[i];
          float4 x0 = h4[i * 8 + part];
          float4 x1 = h4[128 + i * 8 + part];
          a0 += w.x * x0.x + w.y * x0.y + w.z * x0.z + w.w * x0.w;
          a1 += w.x * x1.x + w.y * x1.y + w.z * x1.z + w.w * x1.w;
          float4 v = wi[i];
          float4 y0 = f4v[i * 8 + part];
          float4 y1 = f4v[128 + i * 8 + part];
          c0 += v.x * y0.x + v.y * y0.y + v.z * y0.z + v.w * y0.w;
          c1 += v.x * y1.x + v.y * y1.y + v.z * y1.z + v.w * y1.w;
        }
        a0 += __shfl_xor(a0, 1); a0 += __shfl_xor(a0, 2); a0 += __shfl_xor(a0, 4);
        a1 += __shfl_xor(a1, 1); a1 += __shfl_xor(a1, 2); a1 += __shfl_xor(a1, 4);
        c0 += __shfl_xor(c0, 1); c0 += __shfl_xor(c0, 2); c0 += __shfl_xor(c0, 4);
        c1 += __shfl_xor(c1, 1); c1 += __shfl_xor(c1, 2); c1 += __shfl_xor(c1, 4);
        if (part == 0) { P[r] = a0; P[24 + r] = a1; Q[r] = c0; Q[24 + r] = c1; }
      }
      __syncthreads();
      if (tid < 16) {
        int b = tid >> 3, u2 = tid & 7, j = j0 + u2;
        float i_r = Q[b * 24 + u2] + bi[u2];
        float i_z = Q[b * 24 + 8 + u2] + bi[8 + u2];
        float i_n = Q[b * 24 + 16 + u2] + bi[16 + u2];
        float gh_r = P[b * 24 + u2] + bl[u2];
        float gh_z = P[b * 24 + 8 + u2] + bl[8 + u2];
        float gh_n = P[b * 24 + 16 + u2] + bl[16 + u2];
        float hold = hl[b * 512 + j];
        float rg = 1.0f / (1.0f + __expf(-(i_r + gh_r)));
        float zg = 1.0f / (1.0f + __expf(-(i_z + gh_z)));
        float ng = tanhf(i_n + rg * gh_n);
        float hnew = (1.0f - zg) * ng + zg * hold;
        __hip_atomic_store(ring + (size_t)(t & 3) * 1024 + b * 512 + j, hnew,
                           __ATOMIC_RELAXED, __HIP_MEMORY_SCOPE_AGENT);
        pf_out[(size_t)(b * 512 + t) * 2048 + j] = hnew;
        if (t == 511) hfT[b * 512 + j] = hnew;
      }
      __syncthreads();   // drains vmcnt + keeps waves phase-aligned
      if (tid == 0) post_flag(flagsA, wg, (unsigned)(t + 1));
    }
  } else {
    for (int t2 = 0; t2 < 512; ++t2) {
      if (wave == 0) {
        poll64(flagsA, (unsigned)(t2 + 1), lane);   // p_f(t2) ready
        const unsigned long long* f8 =
            (const unsigned long long*)(ring + (t2 & 3) * 1024);
        unsigned long long v[8];
        #pragma unroll
        for (int k = 0; k < 8; ++k)
          v[k] = __hip_atomic_load(f8 + k * 64 + lane, __ATOMIC_RELAXED,
                                   __HIP_MEMORY_SCOPE_AGENT);
        #pragma unroll
        for (int k = 0; k < 8; ++k) inq[(t2 & 1) * 512 + k * 64 + lane] = v[k];
      } else if (wave == 1) {
        unsigned long long v[8];
        if (t2 == 0) {
          const unsigned long long* s8 = (const unsigned long long*)h0s;
          #pragma unroll
          for (int k = 0; k < 8; ++k) v[k] = s8[k * 64 + lane];
        } else {
          poll64(flagsB, (unsigned)t2, lane);       // h_s(t2-1) ready
          const unsigned long long* s8 =
              (const unsigned long long*)(hsbuf + ((t2 - 1) & 1) * 1024);
          #pragma unroll
          for (int k = 0; k < 8; ++k)
            v[k] = __hip_atomic_load(s8 + k * 64 + lane, __ATOMIC_RELAXED,
                                     __HIP_MEMORY_SCOPE_AGENT);
        }
        #pragma unroll
        for (int k = 0; k < 8; ++k) hlq[k * 64 + lane] = v[k];
      }
      __syncthreads();
      if (r < 24) {
        const float4* f4v = (const float4*)(inb + (t2 & 1) * 1024);
        float a0 = 0.f, a1 = 0.f, c0 = 0.f, c1 = 0.f;
        #pragma unroll
        for (int i = 0; i < 16; ++i) {
          float4 w = wh[i];
          float4 x0 = h4[i * 8 + part];
          float4 x1 = h4[128 + i * 8 + part];
          a0 += w.x * x0.x + w.y * x0.y + w.z * x0.z + w.w * x0.w;
          a1 += w.x * x1.x + w.y * x1.y + w.z * x1.z + w.w * x1.w;
          float4 v = wi[i];
          float4 y0 = f4v[i * 8 + part];
          float4 y1 = f4v[128 + i * 8 + part];
          c0 += v.x * y0.x + v.y * y0.y + v.z * y0.z + v.w * y0.w;
          c1 += v.x * y1.x + v.y * y1.y + v.z * y1.z + v.w * y1.w;
        }
        a0 += __shfl_xor(a0, 1); a0 += __shfl_xor(a0, 2); a0 += __shfl_xor(a0, 4);
        a1 += __shfl_xor(a1, 1); a1 += __shfl_xor(a1, 2); a1 += __shfl_xor(a1, 4);
        c0 += __shfl_xor(c0, 1); c0 += __shfl_xor(c0, 2); c0 += __shfl_xor(c0, 4);
        c1 += __shfl_xor(c1, 1); c1 += __shfl_xor(c1, 2); c1 += __shfl_xor(c1, 4);
        if (part == 0) { P[r] = a0; P[24 + r] = a1; Q[r] = c0; Q[24 + r] = c1; }
      }
      __syncthreads();
      if (tid < 16) {
        int b = tid >> 3, u2 = tid & 7, j = j0 + u2;
        float i_r = Q[b * 24 + u2] + bi[u2];
        float i_z = Q[b * 24 + 8 + u2] + bi[8 + u2];
        float i_n = Q[b * 24 + 16 + u2] + bi[16 + u2];
        float gh_r = P[b * 24 + u2] + bl[u2];
        float gh_z = P[b * 24 + 8 + u2] + bl[8 + u2];
        float gh_n = P[b * 24 + 16 + u2] + bl[16 + u2];
        float hold = hl[b * 512 + j];
        float rg = 1.0f / (1.0f + __expf(-(i_r + gh_r)));
        float zg = 1.0f / (1.0f + __expf(-(i_z + gh_z)));
        float ng = tanhf(i_n + rg * gh_n);
        float hnew = (1.0f - zg) * ng + zg * hold;
        __hip_atomic_store(hsbuf + (size_t)(t2 & 1) * 1024 + b * 512 + j, hnew,
                           __ATOMIC_RELAXED, __HIP_MEMORY_SCOPE_AGENT);
        ps_out[(size_t)(b * 512 + t2) * 512 + j] = hnew;
        if (t2 == 511) hsT[b * 512 + j] = hnew;
      }
      __syncthreads();   // drains vmcnt + keeps waves phase-aligned
      if (tid == 0) post_flag(flagsB, wg - L_WGS, (unsigned)(t2 + 1));
    }
  }
}

// ---------- small kernels ----------
__global__ __launch_bounds__(256) void softmax_kernel(float* __restrict__ a) {
  int m = blockIdx.x, tid = threadIdx.x;
  float v = a[(size_t)m * 256 + tid];
  float mx = v;
  #pragma unroll
  for (int off = 32; off > 0; off >>= 1) mx = fmaxf(mx, __shfl_down(mx, off));
  __shared__ float r4[4];
  __shared__ float s4[4];
  if ((tid & 63) == 0) r4[tid >> 6] = mx;
  __syncthreads();
  mx = fmaxf(fmaxf(r4[0], r4[1]), fmaxf(r4[2], r4[3]));
  float e = __expf(v - mx);
  float s = e;
  #pragma unroll
  for (int off = 32; off > 0; off >>= 1) s += __shfl_down(s, off);
  if ((tid & 63) == 0) s4[tid >> 6] = s;
  __syncthreads();
  s = s4[0] + s4[1] + s4[2] + s4[3];
  a[(size_t)m * 256 + tid] = e / s;
}

__global__ __launch_bounds__(256) void ln_kernel(
    const float* __restrict__ src, const float* __restrict__ src2,
    float* __restrict__ dst, int ldd, int dcoff,
    const float* __restrict__ gv, const float* __restrict__ bv, int tanhFirst) {
  int m = blockIdx.x, tid = threadIdx.x;
  float x0 = src[(size_t)m * 512 + tid];
  float x1 = src[(size_t)m * 512 + 256 + tid];
  if (src2) { x0 += src2[(size_t)m * 512 + tid]; x1 += src2[(size_t)m * 512 + 256 + tid]; }
  if (tanhFirst) { x0 = tanhf(x0); x1 = tanhf(x1); }
  float s = x0 + x1, ss = x0 * x0 + x1 * x1;
  #pragma unroll
  for (int off = 32; off > 0; off >>= 1) { s += __shfl_down(s, off); ss += __shfl_down(ss, off); }
  __shared__ float rs[4], rss[4];
  if ((tid & 63) == 0) { rs[tid >> 6] = s; rss[tid >> 6] = ss; }
  __syncthreads();
  float st = rs[0] + rs[1] + rs[2] + rs[3];
  float sst = rss[0] + rss[1] + rss[2] + rss[3];
  float mean = st * (1.0f / 512.0f);
  float var = sst * (1.0f / 512.0f) - mean * mean;
  float inv = rsqrtf(var + 1e-5f);
  float y0 = (x0 - mean) * inv * gv[tid] + bv[tid];
  float y1 = (x1 - mean) * inv * gv[256 + tid] + bv[256 + tid];
  if (!tanhFirst) { y0 = tanhf(y0); y1 = tanhf(y1); }
  dst[(size_t)m * ldd + dcoff + tid] = y0;
  dst[(size_t)m * ldd + dcoff + 256 + tid] = y1;
}

// inv-norm vector only: swn[r] = 16 / max(||soma_r||, 1e-12)
__global__ __launch_bounds__(256) void swinv_kernel(const float* __restrict__ soma,
                                                    float* __restrict__ swn) {
  int r = blockIdx.x, tid = threadIdx.x;
  float x0 = soma[(size_t)r * 512 + tid];
  float x1 = soma[(size_t)r * 512 + 256 + tid];
  float ss = x0 * x0 + x1 * x1;
  #pragma unroll
  for (int off = 32; off > 0; off >>= 1) ss += __shfl_down(ss, off);
  __shared__ float r4[4];
  if ((tid & 63) == 0) r4[tid >> 6] = ss;
  __syncthreads();
  if (tid == 0) {
    float norm = fmaxf(sqrtf(r4[0] + r4[1] + r4[2] + r4[3]), 1e-12f);
    swn[r] = 16.0f / norm;
  }
}

// ---------- host ----------
extern "C" void kernel_launch(void* const* d_in, const int* in_sizes, int n_in,
                              void* d_out, int out_size, void* d_ws, size_t ws_size,
                              hipStream_t stream) {
  (void)in_sizes; (void)n_in; (void)out_size; (void)ws_size;
  float* W = (float*)d_ws;
  float* outf = (float*)d_out;
  // out layout (floats): logits[262144] | thought[524288] | hf1[1024] | hs1[1024]
  const int* x = (const int*)d_in[0];
  const float* soma = (const float*)d_in[3];

  hipMemsetAsync((char*)d_ws + (size_t)OFF_FLAGS * 4, 0, 16384, stream);
  hipMemsetAsync((char*)d_ws + (size_t)OFF_DEN * 4, 0, 4096, stream);

  // fused GRU1+GRU2 (gi_f computed in-kernel from soma/x; no standalone GEMM)
  gru2_kernel<<<2 * L_WGS, 256, 0, stream>>>(soma, x,
      (const float*)d_in[4], (const float*)d_in[6],
      (const float*)d_in[5], (const float*)d_in[7], (const float*)d_in[1],
      (const float*)d_in[8], (const float*)d_in[10],
      (const float*)d_in[9], (const float*)d_in[11], (const float*)d_in[2],
      W + OFF_COMB, W + OFF_PS, outf + 786432, outf + 787456,
      W + OFF_RING, W + OFF_HSB,
      (unsigned*)(W + OFF_FLAGS), (unsigned*)(W + OFF_FLAGS) + L_WGS * FLAG_STRIDE);

  // merged: qkv (elu+1 on q,k) -> QKV ; gate pre -> TMP ; hip query -> QH
  gemm3<<<dim3(40, 16), 256, 0, stream>>>(W + OFF_PS,
      (const float*)d_in[12], (const float*)d_in[13],
      (const float*)d_in[14], (const float*)d_in[15],
      (const float*)d_in[19], (const float*)d_in[20],
      W + OFF_QKV, W + OFF_TMP, W + OFF_QH);

  // scores = causal(q k^T) per batch, row-sums fused -> DEN
  gemm<<<dim3(8, 16), 256, 0, stream>>>(W + OFF_QKV, 1536, W + OFF_QKV + 512, 1536,
      W + OFF_SCORES, 512, 0, 512, nullptr, nullptr, nullptr, W + OFF_DEN,
      1.f, F_CAUSAL | F_ROWSUM, 512, nullptr, 0);

  // l_mem = (scores @ v) / (den + 1e-6) -> combined cols [1024,1536)
  gemm<<<dim3(8, 16), 256, 0, stream>>>(W + OFF_SCORES, 512, W + OFF_QKV + 1024, 1536,
      W + OFF_COMB, 2048, 1024, 512, nullptr, W + OFF_DEN, nullptr, nullptr,
      1.f, F_NN | F_DIV, 512, nullptr, 0);

  // intent = tanh(LN(gate pre)) -> combined cols [512,1024)
  ln_kernel<<<1024, 256, 0, stream>>>(W + OFF_TMP, nullptr, W + OFF_COMB, 2048, 512,
      (const float*)d_in[16], (const float*)d_in[17], 0);

  // hippocampus attention -> combined cols [1536,2048)
  gemm<<<dim3(4, 16), 256, 0, stream>>>(W + OFF_QH, 512, (const float*)d_in[18], 512,
      W + OFF_ATTN, 256, 0, 512, nullptr, nullptr, nullptr, nullptr,
      0.04419417382415922f, F_SCALE, 0, nullptr, 0);
  softmax_kernel<<<1024, 256, 0, stream>>>(W + OFF_ATTN);
  gemm<<<dim3(8, 16), 256, 0, stream>>>(W + OFF_ATTN, 256, (const float*)d_in[18], 512,
      W + OFF_COMB, 2048, 1536, 256, nullptr, nullptr, nullptr, nullptr,
      1.f, F_NN, 0, nullptr, 0);

  // axon split-K x2 (one 256-block launch): k<1024 -> TMP (+bias), k>=1024 -> QH
  gemm<<<dim3(8, 16, 2), 256, 0, stream>>>(W + OFF_COMB, 2048, (const float*)d_in[21], 2048,
      W + OFF_TMP, 512, 0, 1024, (const float*)d_in[22], nullptr, nullptr, nullptr,
      1.f, 0, 0, W + OFF_QH, 1024);

  // thought = LN(tanh(TMP + QH)) -> out (fp32)
  ln_kernel<<<1024, 256, 0, stream>>>(W + OFF_TMP, W + OFF_QH, outf + 262144, 512, 0,
      (const float*)d_in[23], (const float*)d_in[24], 1);

  // logits = thought @ soma^T scaled by 16/||soma_n|| -> out (fp32)
  swinv_kernel<<<256, 256, 0, stream>>>(soma, W + OFF_SWN);
  gemm<<<dim3(4, 16), 256, 0, stream>>>(outf + 262144, 512, soma, 512,
      outf, 256, 0, 512, nullptr, nullptr, W + OFF_SWN, nullptr,
      1.f, 0, 0, nullptr, 0);
}